// Round 1
// baseline (1537.489 us; speedup 1.0000x reference)
//
#include <hip/hip_runtime.h>

constexpr int N_NODES = 50000;
constexpr int N_EDGES = 800000;
constexpr int IN_F = 64;
constexpr int ED_F = 16;
constexpr int OUT_F = 64;
constexpr int AGG_F = 256;    // 4*IN
constexpr float AVG_D_LOG_F = 2.833f;
constexpr float EPS_F = 1e-5f;

// monotonic float<->int key: int compare order == float compare order (no NaNs in data)
__device__ __forceinline__ int enc(float f) {
    int ix = __float_as_int(f);
    return ix >= 0 ? ix : (ix ^ 0x7fffffff);
}
__device__ __forceinline__ float dec(int k) {
    return __int_as_float(k >= 0 ? k : (k ^ 0x7fffffff));
}

// ---------------- init workspace ----------------
__global__ __launch_bounds__(256) void init_ws_kernel(
    float* __restrict__ sum, float* __restrict__ sumsq,
    int* __restrict__ mxk, int* __restrict__ mnk, int* __restrict__ deg)
{
    int i = blockIdx.x * 256 + threadIdx.x;
    if (i < N_NODES * IN_F) {
        sum[i] = 0.f;
        sumsq[i] = 0.f;
        mxk[i] = enc(-__builtin_inff());
        mnk[i] = enc(__builtin_inff());
    }
    if (i < N_NODES) deg[i] = 0;
}

// ---------------- edge kernel: msg = [h[src],h[dst],ef] @ W_pre + b_pre, atomic segment stats
__global__ __launch_bounds__(256) void edge_kernel(
    const float* __restrict__ h, const float* __restrict__ ef,
    const float* __restrict__ Wpre, const float* __restrict__ bpre,
    const int* __restrict__ src, const int* __restrict__ dst,
    float* __restrict__ sum, float* __restrict__ sumsq,
    int* __restrict__ mxk, int* __restrict__ mnk, int* __restrict__ deg)
{
    __shared__ float WpL[144 * 64];   // 36.9 KB
    int tid = threadIdx.x;
    int lane = tid & 63;
    int wv = tid >> 6;

    for (int i = tid; i < 144 * 64; i += 256) WpL[i] = Wpre[i];
    float bj = bpre[lane];
    __syncthreads();

    int ebase = blockIdx.x * 64 + wv * 16;   // 16 edges per wave, grid exact
    #pragma unroll 2
    for (int t = 0; t < 16; ++t) {
        int e = ebase + t;
        int s = src[e];
        int d = dst[e];
        float zs = h[(size_t)s * IN_F + lane];
        float zd = h[(size_t)d * IN_F + lane];
        float ze = (lane < ED_F) ? ef[(size_t)e * ED_F + lane] : 0.f;

        float acc = bj;
        #pragma unroll
        for (int i = 0; i < 64; ++i)
            acc = fmaf(__shfl(zs, i), WpL[i * 64 + lane], acc);
        #pragma unroll
        for (int i = 0; i < 64; ++i)
            acc = fmaf(__shfl(zd, i), WpL[(64 + i) * 64 + lane], acc);
        #pragma unroll
        for (int i = 0; i < 16; ++i)
            acc = fmaf(__shfl(ze, i), WpL[(128 + i) * 64 + lane], acc);

        size_t base = (size_t)d * IN_F + lane;
        atomicAdd(&sum[base], acc);
        atomicAdd(&sumsq[base], acc * acc);
        atomicMax(&mxk[base], enc(acc));
        atomicMin(&mnk[base], enc(acc));
        if (lane == 0) atomicAdd(&deg[d], 1);
    }
}

// ---------------- node kernel: build agg, fused post-GEMV, graph norm ----------------
// out[j] = b_post[j] + h·W1[:,j] + sum_k agg[k]*(W2[k][j] + a*W3[k][j] + b*W4[k][j]); *snorm
constexpr int NPW = 16;                  // nodes per wave
__global__ __launch_bounds__(256) void node_kernel(
    const float* __restrict__ h, const float* __restrict__ snorm,
    const float* __restrict__ Wpost, const float* __restrict__ bpost,
    const float* __restrict__ sum, const float* __restrict__ sumsq,
    const int* __restrict__ mxk, const int* __restrict__ mnk,
    const int* __restrict__ deg, float* __restrict__ out)
{
    extern __shared__ float smem[];
    // aggL: [4][NPW][AGG_F] = 64KB ; hL: [4][NPW][IN_F] = 16KB
    float* aggL = smem;
    float* hL = smem + 4 * NPW * AGG_F;

    int tid = threadIdx.x;
    int lane = tid & 63;
    int wv = tid >> 6;
    int nbase = blockIdx.x * (4 * NPW) + wv * NPW;

    // phase 1: per-node aggregation stats -> LDS
    for (int t = 0; t < NPW; ++t) {
        int n = nbase + t;
        float mean = 0.f, mx = 0.f, mn = 0.f, sd = 0.f, hv = 0.f;
        if (n < N_NODES) {
            int dg = deg[n];
            float degc = fmaxf((float)dg, 1.f);
            size_t base = (size_t)n * IN_F + lane;
            float s = sum[base];
            float ss = sumsq[base];
            mean = s / degc;
            float msq = ss / degc;
            sd = sqrtf(fmaxf(msq - mean * mean, 0.f) + EPS_F);
            mx = dec(mxk[base]);
            mn = dec(mnk[base]);
            if (dg == 0) { mean = 0.f; mx = 0.f; mn = 0.f; sd = 0.f; }
            hv = h[base];
        }
        int nb = wv * NPW + t;
        aggL[nb * AGG_F + lane] = mean;
        aggL[nb * AGG_F + 64 + lane] = mx;
        aggL[nb * AGG_F + 128 + lane] = mn;
        aggL[nb * AGG_F + 192 + lane] = sd;
        hL[nb * IN_F + lane] = hv;
    }
    __syncthreads();

    // per-node scalers (recomputed per lane; wave-uniform scalar loads)
    float aArr[NPW], bArr[NPW];
    #pragma unroll
    for (int t = 0; t < NPW; ++t) {
        int n = nbase + t;
        int dg = (n < N_NODES) ? deg[n] : 0;
        float degc = fmaxf((float)dg, 1.f);
        float logd = logf(degc + 1.f);
        aArr[t] = logd * (1.f / AVG_D_LOG_F);
        bArr[t] = AVG_D_LOG_F / logd;
    }

    float bp = bpost[lane];
    float acc[NPW];
    #pragma unroll
    for (int t = 0; t < NPW; ++t) acc[t] = bp;

    // h part: rows 0..63 of W_post
    for (int i = 0; i < IN_F; ++i) {
        float w1 = Wpost[i * OUT_F + lane];
        #pragma unroll
        for (int t = 0; t < NPW; ++t)
            acc[t] = fmaf(hL[(wv * NPW + t) * IN_F + i], w1, acc[t]);
    }
    // agg part: rows 64..831 (agg / amp / att sections folded)
    for (int k = 0; k < AGG_F; ++k) {
        float w2 = Wpost[(64 + k) * OUT_F + lane];
        float w3 = Wpost[(320 + k) * OUT_F + lane];
        float w4 = Wpost[(576 + k) * OUT_F + lane];
        #pragma unroll
        for (int t = 0; t < NPW; ++t) {
            float wc = fmaf(aArr[t], w3, w2);
            wc = fmaf(bArr[t], w4, wc);
            acc[t] = fmaf(aggL[(wv * NPW + t) * AGG_F + k], wc, acc[t]);
        }
    }

    #pragma unroll
    for (int t = 0; t < NPW; ++t) {
        int n = nbase + t;
        if (n < N_NODES)
            out[(size_t)n * OUT_F + lane] = acc[t] * snorm[n];
    }
}

extern "C" void kernel_launch(void* const* d_in, const int* in_sizes, int n_in,
                              void* d_out, int out_size, void* d_ws, size_t ws_size,
                              hipStream_t stream) {
    const float* h     = (const float*)d_in[0];
    const float* ef    = (const float*)d_in[1];
    const float* snorm = (const float*)d_in[2];
    const float* Wpre  = (const float*)d_in[3];
    const float* bpre  = (const float*)d_in[4];
    const float* Wpost = (const float*)d_in[5];
    const float* bpost = (const float*)d_in[6];
    const int* src     = (const int*)d_in[7];
    const int* dst     = (const int*)d_in[8];
    float* out = (float*)d_out;

    char* ws = (char*)d_ws;
    const size_t NF = (size_t)N_NODES * IN_F;          // 3.2M
    float* sum   = (float*)(ws);
    float* sumsq = (float*)(ws + NF * 4);
    int*   mxk   = (int*)  (ws + NF * 8);
    int*   mnk   = (int*)  (ws + NF * 12);
    int*   deg   = (int*)  (ws + NF * 16);

    // init: covers N_NODES*IN_F elements
    hipLaunchKernelGGL(init_ws_kernel, dim3((N_NODES * IN_F + 255) / 256), dim3(256), 0, stream,
                       sum, sumsq, mxk, mnk, deg);
    // edges: 64 edges per block, exact grid
    hipLaunchKernelGGL(edge_kernel, dim3(N_EDGES / 64), dim3(256), 0, stream,
                       h, ef, Wpre, bpre, src, dst, sum, sumsq, mxk, mnk, deg);
    // nodes: 64 nodes per block
    size_t smem_bytes = (size_t)(4 * NPW * AGG_F + 4 * NPW * IN_F) * sizeof(float); // 80 KB
    hipLaunchKernelGGL(node_kernel, dim3((N_NODES + 63) / 64), dim3(256), smem_bytes, stream,
                       h, snorm, Wpost, bpost, sum, sumsq, mxk, mnk, deg, out);
}

// Round 3
// 927.413 us; speedup vs baseline: 1.6578x; 1.6578x over previous
//
#include <hip/hip_runtime.h>

constexpr int N_NODES = 50000;
constexpr int N_EDGES = 800000;
constexpr int IN_F = 64;
constexpr int ED_F = 16;
constexpr int OUT_F = 64;
constexpr int AGG_F = 256;    // 4*IN
constexpr float AVG_D_LOG_F = 2.833f;
constexpr float EPS_F = 1e-5f;

// monotonic float<->int key: int compare order == float compare order (no NaNs in data)
__device__ __forceinline__ int enc(float f) {
    int ix = __float_as_int(f);
    return ix >= 0 ? ix : (ix ^ 0x7fffffff);
}
__device__ __forceinline__ float dec(int k) {
    return __int_as_float(k >= 0 ? k : (k ^ 0x7fffffff));
}
// wave-uniform lane broadcast via v_readlane (VALU->SGPR, no LDS traffic)
__device__ __forceinline__ float rl(float v, int l) {
    return __int_as_float(__builtin_amdgcn_readlane(__float_as_int(v), l));
}

// ---------------- init workspace ----------------
__global__ __launch_bounds__(256) void init_ws_kernel(
    float* __restrict__ sum, float* __restrict__ sumsq,
    int* __restrict__ mxk, int* __restrict__ mnk, int* __restrict__ deg)
{
    int i = blockIdx.x * 256 + threadIdx.x;
    if (i < N_NODES * IN_F) {
        sum[i] = 0.f;
        sumsq[i] = 0.f;
        mxk[i] = enc(-__builtin_inff());
        mnk[i] = enc(__builtin_inff());
    }
    if (i < N_NODES) deg[i] = 0;
}

// ---------------- edge kernel: register-blocked GEMM over 16 edges/wave ----------------
constexpr int EPW = 16;   // edges per wave
__global__ __launch_bounds__(256, 3) void edge_kernel(
    const float* __restrict__ h, const float* __restrict__ ef,
    const float* __restrict__ Wpre, const float* __restrict__ bpre,
    const int* __restrict__ src, const int* __restrict__ dst,
    float* __restrict__ sum, float* __restrict__ sumsq,
    int* __restrict__ mxk, int* __restrict__ mnk, int* __restrict__ deg)
{
    __shared__ float WpL[144 * 64];   // 36.9 KB
    int tid = threadIdx.x;
    int lane = tid & 63;
    int wv = tid >> 6;

    for (int i = tid; i < 144 * 64; i += 256) WpL[i] = Wpre[i];
    float bj = bpre[lane];
    __syncthreads();

    int ebase = blockIdx.x * (4 * EPW) + wv * EPW;   // grid exact: 64 edges/block

    int d[EPW];
    float zs[EPW], zd[EPW];
    #pragma unroll
    for (int t = 0; t < EPW; ++t) {
        int s = src[ebase + t];
        d[t] = dst[ebase + t];
        zs[t] = h[(size_t)s * IN_F + lane];
        zd[t] = h[(size_t)d[t] * IN_F + lane];
    }
    // ef for 16 edges = 256 contiguous floats; lane holds 4
    // global idx ebase*16 + lane*4 + c  ->  edge t, feat f at lane t*4+(f>>2), comp f&3
    float4 efv = *reinterpret_cast<const float4*>(ef + (size_t)ebase * ED_F + lane * 4);
    float efa[4] = {efv.x, efv.y, efv.z, efv.w};

    float acc[EPW];
    #pragma unroll
    for (int t = 0; t < EPW; ++t) acc[t] = bj;

    // h[src] rows of W_pre: k = 0..63
    for (int i = 0; i < 64; ++i) {
        float w = WpL[i * 64 + lane];
        #pragma unroll
        for (int t = 0; t < EPW; ++t)
            acc[t] = fmaf(rl(zs[t], i), w, acc[t]);
    }
    // h[dst] rows: k = 64..127
    for (int i = 0; i < 64; ++i) {
        float w = WpL[(64 + i) * 64 + lane];
        #pragma unroll
        for (int t = 0; t < EPW; ++t)
            acc[t] = fmaf(rl(zd[t], i), w, acc[t]);
    }
    // ef rows: k = 128..143 (broadcast lane index is compile-time here)
    #pragma unroll
    for (int f = 0; f < 16; ++f) {
        float w = WpL[(128 + f) * 64 + lane];
        #pragma unroll
        for (int t = 0; t < EPW; ++t)
            acc[t] = fmaf(rl(efa[f & 3], t * 4 + (f >> 2)), w, acc[t]);
    }

    #pragma unroll
    for (int t = 0; t < EPW; ++t) {
        size_t base = (size_t)d[t] * IN_F + lane;
        float a = acc[t];
        atomicAdd(&sum[base], a);
        atomicAdd(&sumsq[base], a * a);
        atomicMax(&mxk[base], enc(a));
        atomicMin(&mnk[base], enc(a));
        if (lane == 0) atomicAdd(&deg[d[t]], 1);
    }
}

// ---------------- node kernel: build agg, fused post-GEMV, graph norm ----------------
// out[j] = b_post[j] + h·W1[:,j] + sum_k agg[k]*(W2[k][j] + a*W3[k][j] + b*W4[k][j]); *snorm
constexpr int NPW = 16;                  // nodes per wave
__global__ __launch_bounds__(256) void node_kernel(
    const float* __restrict__ h, const float* __restrict__ snorm,
    const float* __restrict__ Wpost, const float* __restrict__ bpost,
    const float* __restrict__ sum, const float* __restrict__ sumsq,
    const int* __restrict__ mxk, const int* __restrict__ mnk,
    const int* __restrict__ deg, float* __restrict__ out)
{
    extern __shared__ float smem[];
    // aggL: [4][NPW][AGG_F] = 64KB ; hL: [4][NPW][IN_F] = 16KB
    float* aggL = smem;
    float* hL = smem + 4 * NPW * AGG_F;

    int tid = threadIdx.x;
    int lane = tid & 63;
    int wv = tid >> 6;
    int nbase = blockIdx.x * (4 * NPW) + wv * NPW;

    // phase 1: per-node aggregation stats -> LDS
    for (int t = 0; t < NPW; ++t) {
        int n = nbase + t;
        float mean = 0.f, mx = 0.f, mn = 0.f, sd = 0.f, hv = 0.f;
        if (n < N_NODES) {
            int dg = deg[n];
            float degc = fmaxf((float)dg, 1.f);
            size_t base = (size_t)n * IN_F + lane;
            float s = sum[base];
            float ss = sumsq[base];
            mean = s / degc;
            float msq = ss / degc;
            sd = sqrtf(fmaxf(msq - mean * mean, 0.f) + EPS_F);
            mx = dec(mxk[base]);
            mn = dec(mnk[base]);
            if (dg == 0) { mean = 0.f; mx = 0.f; mn = 0.f; sd = 0.f; }
            hv = h[base];
        }
        int nb = wv * NPW + t;
        aggL[nb * AGG_F + lane] = mean;
        aggL[nb * AGG_F + 64 + lane] = mx;
        aggL[nb * AGG_F + 128 + lane] = mn;
        aggL[nb * AGG_F + 192 + lane] = sd;
        hL[nb * IN_F + lane] = hv;
    }
    __syncthreads();

    // per-node scalers (recomputed per lane; wave-uniform scalar loads)
    float aArr[NPW], bArr[NPW];
    #pragma unroll
    for (int t = 0; t < NPW; ++t) {
        int n = nbase + t;
        int dg = (n < N_NODES) ? deg[n] : 0;
        float degc = fmaxf((float)dg, 1.f);
        float logd = logf(degc + 1.f);
        aArr[t] = logd * (1.f / AVG_D_LOG_F);
        bArr[t] = AVG_D_LOG_F / logd;
    }

    float bp = bpost[lane];
    float acc[NPW];
    #pragma unroll
    for (int t = 0; t < NPW; ++t) acc[t] = bp;

    // h part: rows 0..63 of W_post
    for (int i = 0; i < IN_F; ++i) {
        float w1 = Wpost[i * OUT_F + lane];
        #pragma unroll
        for (int t = 0; t < NPW; ++t)
            acc[t] = fmaf(hL[(wv * NPW + t) * IN_F + i], w1, acc[t]);
    }
    // agg part: rows 64..831 (agg / amp / att sections folded)
    for (int k = 0; k < AGG_F; ++k) {
        float w2 = Wpost[(64 + k) * OUT_F + lane];
        float w3 = Wpost[(320 + k) * OUT_F + lane];
        float w4 = Wpost[(576 + k) * OUT_F + lane];
        #pragma unroll
        for (int t = 0; t < NPW; ++t) {
            float wc = fmaf(aArr[t], w3, w2);
            wc = fmaf(bArr[t], w4, wc);
            acc[t] = fmaf(aggL[(wv * NPW + t) * AGG_F + k], wc, acc[t]);
        }
    }

    #pragma unroll
    for (int t = 0; t < NPW; ++t) {
        int n = nbase + t;
        if (n < N_NODES)
            out[(size_t)n * OUT_F + lane] = acc[t] * snorm[n];
    }
}

extern "C" void kernel_launch(void* const* d_in, const int* in_sizes, int n_in,
                              void* d_out, int out_size, void* d_ws, size_t ws_size,
                              hipStream_t stream) {
    const float* h     = (const float*)d_in[0];
    const float* ef    = (const float*)d_in[1];
    const float* snorm = (const float*)d_in[2];
    const float* Wpre  = (const float*)d_in[3];
    const float* bpre  = (const float*)d_in[4];
    const float* Wpost = (const float*)d_in[5];
    const float* bpost = (const float*)d_in[6];
    const int* src     = (const int*)d_in[7];
    const int* dst     = (const int*)d_in[8];
    float* out = (float*)d_out;

    char* ws = (char*)d_ws;
    const size_t NF = (size_t)N_NODES * IN_F;          // 3.2M
    float* sum   = (float*)(ws);
    float* sumsq = (float*)(ws + NF * 4);
    int*   mxk   = (int*)  (ws + NF * 8);
    int*   mnk   = (int*)  (ws + NF * 12);
    int*   deg   = (int*)  (ws + NF * 16);

    hipLaunchKernelGGL(init_ws_kernel, dim3((N_NODES * IN_F + 255) / 256), dim3(256), 0, stream,
                       sum, sumsq, mxk, mnk, deg);
    hipLaunchKernelGGL(edge_kernel, dim3(N_EDGES / 64), dim3(256), 0, stream,
                       h, ef, Wpre, bpre, src, dst, sum, sumsq, mxk, mnk, deg);
    size_t smem_bytes = (size_t)(4 * NPW * AGG_F + 4 * NPW * IN_F) * sizeof(float); // 80 KB
    hipLaunchKernelGGL(node_kernel, dim3((N_NODES + 63) / 64), dim3(256), smem_bytes, stream,
                       h, snorm, Wpost, bpost, sum, sumsq, mxk, mnk, deg, out);
}

// Round 4
// 473.200 us; speedup vs baseline: 3.2491x; 1.9599x over previous
//
#include <hip/hip_runtime.h>

constexpr int N_NODES = 50000;
constexpr int N_EDGES = 800000;
constexpr int IN_F = 64;
constexpr int ED_F = 16;
constexpr int OUT_F = 64;
constexpr int AGG_F = 256;    // 4*IN
constexpr float AVG_D_LOG_F = 2.833f;
constexpr float EPS_F = 1e-5f;

// wave-uniform lane broadcast via v_readlane (VALU->SGPR, no LDS traffic)
__device__ __forceinline__ float rl(float v, int l) {
    return __int_as_float(__builtin_amdgcn_readlane(__float_as_int(v), l));
}

// ---------------- P1 = h@Wpre[0:64], P2 = h@Wpre[64:128] + b_pre ----------------
__global__ __launch_bounds__(256) void p12_kernel(
    const float* __restrict__ h, const float* __restrict__ Wpre, const float* __restrict__ bpre,
    float* __restrict__ P1, float* __restrict__ P2)
{
    __shared__ float WpL[128 * 64];   // 32 KB: rows 0..127
    int tid = threadIdx.x;
    int lane = tid & 63;
    int wv = tid >> 6;
    for (int i = tid; i < 128 * 64; i += 256) WpL[i] = Wpre[i];
    float bj = bpre[lane];
    __syncthreads();

    int nbase = blockIdx.x * 64 + wv * 16;
    float hr[16];
    #pragma unroll
    for (int t = 0; t < 16; ++t) {
        int n = nbase + t; if (n >= N_NODES) n = N_NODES - 1;
        hr[t] = h[(size_t)n * IN_F + lane];
    }
    float p1[16], p2[16];
    #pragma unroll
    for (int t = 0; t < 16; ++t) { p1[t] = 0.f; p2[t] = bj; }

    for (int i = 0; i < 64; ++i) {
        float w1 = WpL[i * 64 + lane];
        float w2 = WpL[(64 + i) * 64 + lane];
        #pragma unroll
        for (int t = 0; t < 16; ++t) {
            float x = rl(hr[t], i);
            p1[t] = fmaf(x, w1, p1[t]);
            p2[t] = fmaf(x, w2, p2[t]);
        }
    }
    #pragma unroll
    for (int t = 0; t < 16; ++t) {
        int n = nbase + t;
        if (n < N_NODES) {
            P1[(size_t)n * IN_F + lane] = p1[t];
            P2[(size_t)n * IN_F + lane] = p2[t];
        }
    }
}

// ---------------- degree histogram ----------------
__global__ __launch_bounds__(256) void hist_kernel(const int* __restrict__ dst, int* __restrict__ deg)
{
    int e = blockIdx.x * 256 + threadIdx.x;
    if (e < N_EDGES) atomicAdd(&deg[dst[e]], 1);
}

// ---------------- exclusive scan of deg -> row_start, cursor (single block) ----------------
constexpr int SCAN_PER_T = 49;   // 1024*49 = 50176 >= N_NODES
__global__ __launch_bounds__(1024) void scan_kernel(
    const int* __restrict__ deg, int* __restrict__ row_start, int* __restrict__ cursor)
{
    __shared__ int wsum[16];
    int t = threadIdx.x;
    int lane = t & 63, wv = t >> 6;
    int base = t * SCAN_PER_T;

    int s = 0;
    for (int i = 0; i < SCAN_PER_T; ++i) {
        int idx = base + i;
        if (idx < N_NODES) s += deg[idx];
    }
    // wave inclusive scan
    int sc = s;
    #pragma unroll
    for (int off = 1; off < 64; off <<= 1) {
        int u = __shfl_up(sc, off);
        if (lane >= off) sc += u;
    }
    if (lane == 63) wsum[wv] = sc;
    __syncthreads();
    if (wv == 0 && lane < 16) {
        int v = wsum[lane];
        #pragma unroll
        for (int off = 1; off < 16; off <<= 1) {
            int u = __shfl_up(v, off);
            if (lane >= off) v += u;
        }
        wsum[lane] = v;
    }
    __syncthreads();
    int wbase = (wv > 0) ? wsum[wv - 1] : 0;
    int run = wbase + (sc - s);   // exclusive prefix for this thread's chunk
    for (int i = 0; i < SCAN_PER_T; ++i) {
        int idx = base + i;
        if (idx < N_NODES) {
            row_start[idx] = run;
            cursor[idx] = run;
            run += deg[idx];
        }
    }
}

// ---------------- scatter edge ids into CSR slots ----------------
__global__ __launch_bounds__(256) void scatter_kernel(
    const int* __restrict__ dst, int* __restrict__ cursor, int* __restrict__ csr)
{
    int e = blockIdx.x * 256 + threadIdx.x;
    if (e < N_EDGES) {
        int pos = atomicAdd(&cursor[dst[e]], 1);
        csr[pos] = e;
    }
}

// ---------------- aggregation: one wave per node, stats in registers ----------------
__global__ __launch_bounds__(256) void agg_kernel(
    const float* __restrict__ P1, const float* __restrict__ P2,
    const float* __restrict__ ef, const float* __restrict__ Wpre,
    const int* __restrict__ src, const int* __restrict__ csr,
    const int* __restrict__ row_start, const int* __restrict__ deg,
    float* __restrict__ agg)
{
    __shared__ float WefL[16 * 64];   // 4 KB: Wpre rows 128..143
    int tid = threadIdx.x;
    int lane = tid & 63;
    int wv = tid >> 6;
    for (int i = tid; i < 16 * 64; i += 256) WefL[i] = Wpre[128 * 64 + i];
    __syncthreads();

    int n = blockIdx.x * 4 + wv;
    if (n >= N_NODES) return;
    int rs = row_start[n];
    int dg = deg[n];
    size_t obase = (size_t)n * AGG_F + lane;

    if (dg == 0) {
        agg[obase] = 0.f; agg[obase + 64] = 0.f;
        agg[obase + 128] = 0.f; agg[obase + 192] = 0.f;
        return;
    }

    float p2n = P2[(size_t)n * IN_F + lane];
    float sum = 0.f, ssq = 0.f;
    float mx = -__builtin_inff(), mn = __builtin_inff();

    // 1-ahead prefetch of (edge id, src id)
    int e0 = csr[rs];
    int s0 = src[e0];
    for (int i = 0; i < dg; ++i) {
        float p1 = P1[(size_t)s0 * IN_F + lane];
        float efv = (lane < ED_F) ? ef[(size_t)e0 * ED_F + lane] : 0.f;
        if (i + 1 < dg) { e0 = csr[rs + i + 1]; s0 = src[e0]; }
        float m = p2n;
        #pragma unroll
        for (int f = 0; f < 16; ++f)
            m = fmaf(rl(efv, f), WefL[f * 64 + lane], m);
        m += p1;
        sum += m;
        ssq = fmaf(m, m, ssq);
        mx = fmaxf(mx, m);
        mn = fminf(mn, m);
    }

    float degc = (float)dg;     // dg >= 1 here
    float mean = sum / degc;
    float msq = ssq / degc;
    float sd = sqrtf(fmaxf(msq - mean * mean, 0.f) + EPS_F);
    agg[obase] = mean;
    agg[obase + 64] = mx;
    agg[obase + 128] = mn;
    agg[obase + 192] = sd;
}

// ---------------- post: out = [h,agg,amp,att]@W_post + b; *snorm ----------------
constexpr int NPW = 8;                  // nodes per wave
__global__ __launch_bounds__(256) void post_kernel(
    const float* __restrict__ h, const float* __restrict__ snorm,
    const float* __restrict__ Wpost, const float* __restrict__ bpost,
    const float* __restrict__ agg, const int* __restrict__ deg,
    float* __restrict__ out)
{
    extern __shared__ float smem[];
    float* aggL = smem;                       // [4*NPW][AGG_F]
    float* hL = smem + 4 * NPW * AGG_F;       // [4*NPW][IN_F]

    int tid = threadIdx.x;
    int lane = tid & 63;
    int wv = tid >> 6;
    int nbase = blockIdx.x * (4 * NPW) + wv * NPW;

    for (int t = 0; t < NPW; ++t) {
        int n = nbase + t;
        int nb = wv * NPW + t;
        if (n < N_NODES) {
            size_t ab = (size_t)n * AGG_F + lane;
            aggL[nb * AGG_F + lane]       = agg[ab];
            aggL[nb * AGG_F + 64 + lane]  = agg[ab + 64];
            aggL[nb * AGG_F + 128 + lane] = agg[ab + 128];
            aggL[nb * AGG_F + 192 + lane] = agg[ab + 192];
            hL[nb * IN_F + lane] = h[(size_t)n * IN_F + lane];
        } else {
            aggL[nb * AGG_F + lane] = 0.f; aggL[nb * AGG_F + 64 + lane] = 0.f;
            aggL[nb * AGG_F + 128 + lane] = 0.f; aggL[nb * AGG_F + 192 + lane] = 0.f;
            hL[nb * IN_F + lane] = 0.f;
        }
    }
    __syncthreads();

    float aArr[NPW], bArr[NPW];
    #pragma unroll
    for (int t = 0; t < NPW; ++t) {
        int n = nbase + t;
        int dg = (n < N_NODES) ? deg[n] : 0;
        float degc = fmaxf((float)dg, 1.f);
        float logd = logf(degc + 1.f);
        aArr[t] = logd * (1.f / AVG_D_LOG_F);
        bArr[t] = AVG_D_LOG_F / logd;
    }

    float bp = bpost[lane];
    float acc[NPW];
    #pragma unroll
    for (int t = 0; t < NPW; ++t) acc[t] = bp;

    for (int i = 0; i < IN_F; ++i) {
        float w1 = Wpost[i * OUT_F + lane];
        #pragma unroll
        for (int t = 0; t < NPW; ++t)
            acc[t] = fmaf(hL[(wv * NPW + t) * IN_F + i], w1, acc[t]);
    }
    for (int k = 0; k < AGG_F; ++k) {
        float w2 = Wpost[(64 + k) * OUT_F + lane];
        float w3 = Wpost[(320 + k) * OUT_F + lane];
        float w4 = Wpost[(576 + k) * OUT_F + lane];
        #pragma unroll
        for (int t = 0; t < NPW; ++t) {
            float wc = fmaf(aArr[t], w3, w2);
            wc = fmaf(bArr[t], w4, wc);
            acc[t] = fmaf(aggL[(wv * NPW + t) * AGG_F + k], wc, acc[t]);
        }
    }

    #pragma unroll
    for (int t = 0; t < NPW; ++t) {
        int n = nbase + t;
        if (n < N_NODES)
            out[(size_t)n * OUT_F + lane] = acc[t] * snorm[n];
    }
}

extern "C" void kernel_launch(void* const* d_in, const int* in_sizes, int n_in,
                              void* d_out, int out_size, void* d_ws, size_t ws_size,
                              hipStream_t stream) {
    const float* h     = (const float*)d_in[0];
    const float* ef    = (const float*)d_in[1];
    const float* snorm = (const float*)d_in[2];
    const float* Wpre  = (const float*)d_in[3];
    const float* bpre  = (const float*)d_in[4];
    const float* Wpost = (const float*)d_in[5];
    const float* bpost = (const float*)d_in[6];
    const int* src     = (const int*)d_in[7];
    const int* dst     = (const int*)d_in[8];
    float* out = (float*)d_out;

    char* ws = (char*)d_ws;
    size_t off = 0;
    auto alloc = [&](size_t bytes) { char* p = ws + off; off += (bytes + 255) & ~size_t(255); return p; };
    float* P1      = (float*)alloc((size_t)N_NODES * IN_F * 4);    // 12.8 MB
    float* P2      = (float*)alloc((size_t)N_NODES * IN_F * 4);    // 12.8 MB
    float* agg     = (float*)alloc((size_t)N_NODES * AGG_F * 4);   // 51.2 MB
    int* deg       = (int*)alloc((size_t)N_NODES * 4);
    int* row_start = (int*)alloc((size_t)N_NODES * 4);
    int* cursor    = (int*)alloc((size_t)N_NODES * 4);
    int* csr       = (int*)alloc((size_t)N_EDGES * 4);             // 3.2 MB

    hipMemsetAsync(deg, 0, (size_t)N_NODES * 4, stream);
    hipLaunchKernelGGL(p12_kernel, dim3((N_NODES + 63) / 64), dim3(256), 0, stream,
                       h, Wpre, bpre, P1, P2);
    hipLaunchKernelGGL(hist_kernel, dim3((N_EDGES + 255) / 256), dim3(256), 0, stream, dst, deg);
    hipLaunchKernelGGL(scan_kernel, dim3(1), dim3(1024), 0, stream, deg, row_start, cursor);
    hipLaunchKernelGGL(scatter_kernel, dim3((N_EDGES + 255) / 256), dim3(256), 0, stream,
                       dst, cursor, csr);
    hipLaunchKernelGGL(agg_kernel, dim3((N_NODES + 3) / 4), dim3(256), 0, stream,
                       P1, P2, ef, Wpre, src, csr, row_start, deg, agg);
    size_t smem_bytes = (size_t)(4 * NPW * AGG_F + 4 * NPW * IN_F) * sizeof(float); // 40 KB
    hipLaunchKernelGGL(post_kernel, dim3((N_NODES + 4 * NPW - 1) / (4 * NPW)), dim3(256), smem_bytes, stream,
                       h, snorm, Wpost, bpost, agg, deg, out);
}

// Round 5
// 351.418 us; speedup vs baseline: 4.3751x; 1.3465x over previous
//
#include <hip/hip_runtime.h>

constexpr int N_NODES = 50000;
constexpr int N_EDGES = 800000;
constexpr int IN_F = 64;
constexpr int ED_F = 16;
constexpr int OUT_F = 64;
constexpr int AGG_F = 256;    // 4*IN
constexpr float AVG_D_LOG_F = 2.833f;
constexpr float EPS_F = 1e-5f;

__device__ __forceinline__ float rl(float v, int l) {
    return __int_as_float(__builtin_amdgcn_readlane(__float_as_int(v), l));
}
__device__ __forceinline__ int rfl(int v) { return __builtin_amdgcn_readfirstlane(v); }

// ---------------- P1 = h@Wpre[0:64], P2 = h@Wpre[64:128] + b_pre ----------------
__global__ __launch_bounds__(256) void p12_kernel(
    const float* __restrict__ h, const float* __restrict__ Wpre, const float* __restrict__ bpre,
    float* __restrict__ P1, float* __restrict__ P2)
{
    __shared__ float WpL[128 * 64];   // 32 KB
    int tid = threadIdx.x;
    int lane = tid & 63;
    int wv = tid >> 6;
    for (int i = tid; i < 128 * 64; i += 256) WpL[i] = Wpre[i];
    float bj = bpre[lane];
    __syncthreads();

    int nbase = blockIdx.x * 64 + wv * 16;
    float hr[16];
    #pragma unroll
    for (int t = 0; t < 16; ++t) {
        int n = nbase + t; if (n >= N_NODES) n = N_NODES - 1;
        hr[t] = h[(size_t)n * IN_F + lane];
    }
    float p1[16], p2[16];
    #pragma unroll
    for (int t = 0; t < 16; ++t) { p1[t] = 0.f; p2[t] = bj; }

    for (int i = 0; i < 64; ++i) {
        float w1 = WpL[i * 64 + lane];
        float w2 = WpL[(64 + i) * 64 + lane];
        #pragma unroll
        for (int t = 0; t < 16; ++t) {
            float x = rl(hr[t], i);
            p1[t] = fmaf(x, w1, p1[t]);
            p2[t] = fmaf(x, w2, p2[t]);
        }
    }
    #pragma unroll
    for (int t = 0; t < 16; ++t) {
        int n = nbase + t;
        if (n < N_NODES) {
            P1[(size_t)n * IN_F + lane] = p1[t];
            P2[(size_t)n * IN_F + lane] = p2[t];
        }
    }
}

// ---------------- degree histogram ----------------
__global__ __launch_bounds__(256) void hist_kernel(const int* __restrict__ dst, int* __restrict__ deg)
{
    int e = blockIdx.x * 256 + threadIdx.x;
    if (e < N_EDGES) atomicAdd(&deg[dst[e]], 1);
}

// ---------------- 3-phase coalesced scan ----------------
constexpr int NBLK_SCAN = (N_NODES + 255) / 256;   // 196

__global__ __launch_bounds__(256) void scan1_kernel(const int* __restrict__ deg, int* __restrict__ bsum)
{
    __shared__ int ws[4];
    int tid = threadIdx.x, lane = tid & 63, wv = tid >> 6;
    int i = blockIdx.x * 256 + tid;
    int v = (i < N_NODES) ? deg[i] : 0;
    #pragma unroll
    for (int off = 32; off > 0; off >>= 1) v += __shfl_down(v, off);
    if (lane == 0) ws[wv] = v;
    __syncthreads();
    if (tid == 0) bsum[blockIdx.x] = ws[0] + ws[1] + ws[2] + ws[3];
}

__global__ __launch_bounds__(256) void scan2_kernel(const int* __restrict__ bsum, int* __restrict__ bpre)
{
    __shared__ int ws[4];
    int tid = threadIdx.x, lane = tid & 63, wv = tid >> 6;
    int v = (tid < NBLK_SCAN) ? bsum[tid] : 0;
    int sc = v;
    #pragma unroll
    for (int off = 1; off < 64; off <<= 1) {
        int u = __shfl_up(sc, off);
        if (lane >= off) sc += u;
    }
    if (lane == 63) ws[wv] = sc;
    __syncthreads();
    int wbase = 0;
    #pragma unroll
    for (int w = 0; w < 4; ++w) if (w < wv) wbase += ws[w];
    if (tid < NBLK_SCAN) bpre[tid] = wbase + sc - v;   // exclusive
}

__global__ __launch_bounds__(256) void scan3_kernel(
    const int* __restrict__ deg, const int* __restrict__ bpre,
    int* __restrict__ row_start, int* __restrict__ cursor)
{
    __shared__ int ws[4];
    int tid = threadIdx.x, lane = tid & 63, wv = tid >> 6;
    int i = blockIdx.x * 256 + tid;
    int v = (i < N_NODES) ? deg[i] : 0;
    int sc = v;
    #pragma unroll
    for (int off = 1; off < 64; off <<= 1) {
        int u = __shfl_up(sc, off);
        if (lane >= off) sc += u;
    }
    if (lane == 63) ws[wv] = sc;
    __syncthreads();
    int wbase = 0;
    #pragma unroll
    for (int w = 0; w < 4; ++w) if (w < wv) wbase += ws[w];
    int ex = bpre[blockIdx.x] + wbase + sc - v;
    if (i < N_NODES) { row_start[i] = ex; cursor[i] = ex; }
}

// ---------------- scatter edge ids into CSR slots ----------------
__global__ __launch_bounds__(256) void scatter_kernel(
    const int* __restrict__ dst, int* __restrict__ cursor, int* __restrict__ csr)
{
    int e = blockIdx.x * 256 + threadIdx.x;
    if (e < N_EDGES) {
        int pos = atomicAdd(&cursor[dst[e]], 1);
        csr[pos] = e;
    }
}

// ---------------- aggregation: one wave per node, scalar-uniform CSR walk ----------------
__global__ __launch_bounds__(256) void agg_kernel(
    const float* __restrict__ P1, const float* __restrict__ P2,
    const float* __restrict__ ef, const float* __restrict__ Wpre,
    const int* __restrict__ src, const int* __restrict__ csr,
    const int* __restrict__ row_start, const int* __restrict__ deg,
    float* __restrict__ agg)
{
    int tid = threadIdx.x;
    int lane = tid & 63;

    // Wef column held in registers (16 VGPRs), loaded straight from global (cached)
    float wef[16];
    #pragma unroll
    for (int f = 0; f < 16; ++f) wef[f] = Wpre[(128 + f) * 64 + lane];

    int n = rfl(blockIdx.x * 4 + (tid >> 6));    // wave-uniform in SGPR
    if (n >= N_NODES) return;
    int rs = rfl(row_start[n]);                  // scalar loads
    int dg = rfl(deg[n]);
    size_t obase = (size_t)n * AGG_F + lane;

    if (dg == 0) {
        agg[obase] = 0.f; agg[obase + 64] = 0.f;
        agg[obase + 128] = 0.f; agg[obase + 192] = 0.f;
        return;
    }

    float p2n = P2[(size_t)n * IN_F + lane];
    float sum = 0.f, ssq = 0.f;
    float mx = -__builtin_inff(), mn = __builtin_inff();

    int e_cur = rfl(csr[rs]);
    int s_cur = rfl(src[e_cur]);
    float efs[16];
    #pragma unroll
    for (int f = 0; f < 16; ++f) efs[f] = ef[(size_t)e_cur * ED_F + f];  // s_load (uniform)

    for (int i = 0; i < dg; ++i) {
        float p1 = P1[(size_t)s_cur * IN_F + lane];
        // q = ef_e @ Wef, two chains for latency
        float q0 = 0.f, q1 = 0.f;
        #pragma unroll
        for (int f = 0; f < 8; ++f) {
            q0 = fmaf(efs[2 * f], wef[2 * f], q0);
            q1 = fmaf(efs[2 * f + 1], wef[2 * f + 1], q1);
        }
        if (i + 1 < dg) {
            int e_nxt = rfl(csr[rs + i + 1]);
            s_cur = rfl(src[e_nxt]);
            #pragma unroll
            for (int f = 0; f < 16; ++f) efs[f] = ef[(size_t)e_nxt * ED_F + f];
        }
        float x = p1 + q0 + q1;       // msg minus constant p2n
        sum += x;
        ssq = fmaf(x, x, ssq);
        mx = fmaxf(mx, x);
        mn = fminf(mn, x);
    }

    float degc = (float)dg;
    float mean_x = sum / degc;
    float sd = sqrtf(fmaxf(ssq / degc - mean_x * mean_x, 0.f) + EPS_F);  // shift-invariant
    agg[obase]       = mean_x + p2n;
    agg[obase + 64]  = mx + p2n;
    agg[obase + 128] = mn + p2n;
    agg[obase + 192] = sd;
}

// ---------------- post: out = [h,agg,amp,att]@W_post + b; *snorm ----------------
constexpr int NPW = 16;                  // nodes per wave
__global__ __launch_bounds__(256) void post_kernel(
    const float* __restrict__ h, const float* __restrict__ snorm,
    const float* __restrict__ Wpost, const float* __restrict__ bpost,
    const float* __restrict__ agg, const int* __restrict__ deg,
    float* __restrict__ out)
{
    extern __shared__ float smem[];
    float* aggL = smem;                       // [4*NPW][AGG_F] = 64 KB
    float* hL = smem + 4 * NPW * AGG_F;       // [4*NPW][IN_F]  = 16 KB

    int tid = threadIdx.x;
    int lane = tid & 63;
    int wv = tid >> 6;
    int nbase = rfl(blockIdx.x * (4 * NPW) + wv * NPW);

    for (int t = 0; t < NPW; ++t) {
        int n = nbase + t;
        int nb = wv * NPW + t;
        if (n < N_NODES) {
            size_t ab = (size_t)n * AGG_F + lane;
            aggL[nb * AGG_F + lane]       = agg[ab];
            aggL[nb * AGG_F + 64 + lane]  = agg[ab + 64];
            aggL[nb * AGG_F + 128 + lane] = agg[ab + 128];
            aggL[nb * AGG_F + 192 + lane] = agg[ab + 192];
            hL[nb * IN_F + lane] = h[(size_t)n * IN_F + lane];
        } else {
            aggL[nb * AGG_F + lane] = 0.f; aggL[nb * AGG_F + 64 + lane] = 0.f;
            aggL[nb * AGG_F + 128 + lane] = 0.f; aggL[nb * AGG_F + 192 + lane] = 0.f;
            hL[nb * IN_F + lane] = 0.f;
        }
    }
    __syncthreads();

    float aArr[NPW], bArr[NPW];
    #pragma unroll
    for (int t = 0; t < NPW; ++t) {
        int n = nbase + t;
        int dg = (n < N_NODES) ? deg[n] : 0;   // scalar load (nbase uniform)
        float degc = fmaxf((float)dg, 1.f);
        float logd = logf(degc + 1.f);
        aArr[t] = logd * (1.f / AVG_D_LOG_F);
        bArr[t] = AVG_D_LOG_F / logd;
    }

    float bp = bpost[lane];
    float acc[NPW];
    #pragma unroll
    for (int t = 0; t < NPW; ++t) acc[t] = bp;

    // h part: rows 0..63, vectorized LDS reads
    for (int i4 = 0; i4 < IN_F; i4 += 4) {
        float w1[4];
        #pragma unroll
        for (int j = 0; j < 4; ++j) w1[j] = Wpost[(i4 + j) * OUT_F + lane];
        #pragma unroll
        for (int t = 0; t < NPW; ++t) {
            float4 h4 = *reinterpret_cast<const float4*>(&hL[(wv * NPW + t) * IN_F + i4]);
            acc[t] = fmaf(h4.x, w1[0], acc[t]);
            acc[t] = fmaf(h4.y, w1[1], acc[t]);
            acc[t] = fmaf(h4.z, w1[2], acc[t]);
            acc[t] = fmaf(h4.w, w1[3], acc[t]);
        }
    }
    // agg part: rows 64..831 folded (agg/amp/att), vectorized LDS reads
    for (int k4 = 0; k4 < AGG_F; k4 += 4) {
        float w2[4], w3[4], w4[4];
        #pragma unroll
        for (int j = 0; j < 4; ++j) {
            w2[j] = Wpost[(64 + k4 + j) * OUT_F + lane];
            w3[j] = Wpost[(320 + k4 + j) * OUT_F + lane];
            w4[j] = Wpost[(576 + k4 + j) * OUT_F + lane];
        }
        #pragma unroll
        for (int t = 0; t < NPW; ++t) {
            float4 a4 = *reinterpret_cast<const float4*>(&aggL[(wv * NPW + t) * AGG_F + k4]);
            float av[4] = {a4.x, a4.y, a4.z, a4.w};
            #pragma unroll
            for (int j = 0; j < 4; ++j) {
                float wc = fmaf(aArr[t], w3[j], w2[j]);
                wc = fmaf(bArr[t], w4[j], wc);
                acc[t] = fmaf(av[j], wc, acc[t]);
            }
        }
    }

    #pragma unroll
    for (int t = 0; t < NPW; ++t) {
        int n = nbase + t;
        if (n < N_NODES)
            out[(size_t)n * OUT_F + lane] = acc[t] * snorm[n];
    }
}

extern "C" void kernel_launch(void* const* d_in, const int* in_sizes, int n_in,
                              void* d_out, int out_size, void* d_ws, size_t ws_size,
                              hipStream_t stream) {
    const float* h     = (const float*)d_in[0];
    const float* ef    = (const float*)d_in[1];
    const float* snorm = (const float*)d_in[2];
    const float* Wpre  = (const float*)d_in[3];
    const float* bpre  = (const float*)d_in[4];
    const float* Wpost = (const float*)d_in[5];
    const float* bpost = (const float*)d_in[6];
    const int* src     = (const int*)d_in[7];
    const int* dst     = (const int*)d_in[8];
    float* out = (float*)d_out;

    char* ws = (char*)d_ws;
    size_t off = 0;
    auto alloc = [&](size_t bytes) { char* p = ws + off; off += (bytes + 255) & ~size_t(255); return p; };
    float* P1      = (float*)alloc((size_t)N_NODES * IN_F * 4);
    float* P2      = (float*)alloc((size_t)N_NODES * IN_F * 4);
    float* agg     = (float*)alloc((size_t)N_NODES * AGG_F * 4);
    int* deg       = (int*)alloc((size_t)N_NODES * 4);
    int* row_start = (int*)alloc((size_t)N_NODES * 4);
    int* cursor    = (int*)alloc((size_t)N_NODES * 4);
    int* csr       = (int*)alloc((size_t)N_EDGES * 4);
    int* bsum      = (int*)alloc((size_t)NBLK_SCAN * 4);
    int* bpre2     = (int*)alloc((size_t)NBLK_SCAN * 4);

    hipMemsetAsync(deg, 0, (size_t)N_NODES * 4, stream);
    hipLaunchKernelGGL(p12_kernel, dim3((N_NODES + 63) / 64), dim3(256), 0, stream,
                       h, Wpre, bpre, P1, P2);
    hipLaunchKernelGGL(hist_kernel, dim3((N_EDGES + 255) / 256), dim3(256), 0, stream, dst, deg);
    hipLaunchKernelGGL(scan1_kernel, dim3(NBLK_SCAN), dim3(256), 0, stream, deg, bsum);
    hipLaunchKernelGGL(scan2_kernel, dim3(1), dim3(256), 0, stream, bsum, bpre2);
    hipLaunchKernelGGL(scan3_kernel, dim3(NBLK_SCAN), dim3(256), 0, stream, deg, bpre2, row_start, cursor);
    hipLaunchKernelGGL(scatter_kernel, dim3((N_EDGES + 255) / 256), dim3(256), 0, stream,
                       dst, cursor, csr);
    hipLaunchKernelGGL(agg_kernel, dim3((N_NODES + 3) / 4), dim3(256), 0, stream,
                       P1, P2, ef, Wpre, src, csr, row_start, deg, agg);
    size_t smem_bytes = (size_t)(4 * NPW * AGG_F + 4 * NPW * IN_F) * sizeof(float); // 80 KB
    hipLaunchKernelGGL(post_kernel, dim3((N_NODES + 4 * NPW - 1) / (4 * NPW)), dim3(256), smem_bytes, stream,
                       h, snorm, Wpost, bpost, agg, deg, out);
}

// Round 6
// 322.061 us; speedup vs baseline: 4.7739x; 1.0912x over previous
//
#include <hip/hip_runtime.h>

constexpr int N_NODES = 50000;
constexpr int N_EDGES = 800000;
constexpr int IN_F = 64;
constexpr int ED_F = 16;
constexpr int OUT_F = 64;
constexpr int AGG_F = 256;    // 4*IN
constexpr float AVG_D_LOG_F = 2.833f;
constexpr float EPS_F = 1e-5f;

__device__ __forceinline__ float rl(float v, int l) {
    return __int_as_float(__builtin_amdgcn_readlane(__float_as_int(v), l));
}
__device__ __forceinline__ int rfl(int v) { return __builtin_amdgcn_readfirstlane(v); }

// ---------------- P1 = h@Wpre[0:64], P2 = h@Wpre[64:128] + b_pre ----------------
__global__ __launch_bounds__(256) void p12_kernel(
    const float* __restrict__ h, const float* __restrict__ Wpre, const float* __restrict__ bpre,
    float* __restrict__ P1, float* __restrict__ P2)
{
    __shared__ float WpL[128 * 64];   // 32 KB
    int tid = threadIdx.x;
    int lane = tid & 63;
    int wv = tid >> 6;
    for (int i = tid; i < 128 * 64; i += 256) WpL[i] = Wpre[i];
    float bj = bpre[lane];
    __syncthreads();

    int nbase = blockIdx.x * 64 + wv * 16;
    float hr[16];
    #pragma unroll
    for (int t = 0; t < 16; ++t) {
        int n = nbase + t; if (n >= N_NODES) n = N_NODES - 1;
        hr[t] = h[(size_t)n * IN_F + lane];
    }
    float p1[16], p2[16];
    #pragma unroll
    for (int t = 0; t < 16; ++t) { p1[t] = 0.f; p2[t] = bj; }

    for (int i = 0; i < 64; ++i) {
        float w1 = WpL[i * 64 + lane];
        float w2 = WpL[(64 + i) * 64 + lane];
        #pragma unroll
        for (int t = 0; t < 16; ++t) {
            float x = rl(hr[t], i);
            p1[t] = fmaf(x, w1, p1[t]);
            p2[t] = fmaf(x, w2, p2[t]);
        }
    }
    #pragma unroll
    for (int t = 0; t < 16; ++t) {
        int n = nbase + t;
        if (n < N_NODES) {
            P1[(size_t)n * IN_F + lane] = p1[t];
            P2[(size_t)n * IN_F + lane] = p2[t];
        }
    }
}

// ---------------- degree histogram ----------------
__global__ __launch_bounds__(256) void hist_kernel(const int* __restrict__ dst, int* __restrict__ deg)
{
    int e = blockIdx.x * 256 + threadIdx.x;
    if (e < N_EDGES) atomicAdd(&deg[dst[e]], 1);
}

// ---------------- 3-phase coalesced scan ----------------
constexpr int NBLK_SCAN = (N_NODES + 255) / 256;   // 196

__global__ __launch_bounds__(256) void scan1_kernel(const int* __restrict__ deg, int* __restrict__ bsum)
{
    __shared__ int ws[4];
    int tid = threadIdx.x, lane = tid & 63, wv = tid >> 6;
    int i = blockIdx.x * 256 + tid;
    int v = (i < N_NODES) ? deg[i] : 0;
    #pragma unroll
    for (int off = 32; off > 0; off >>= 1) v += __shfl_down(v, off);
    if (lane == 0) ws[wv] = v;
    __syncthreads();
    if (tid == 0) bsum[blockIdx.x] = ws[0] + ws[1] + ws[2] + ws[3];
}

__global__ __launch_bounds__(256) void scan2_kernel(const int* __restrict__ bsum, int* __restrict__ bpre)
{
    __shared__ int ws[4];
    int tid = threadIdx.x, lane = tid & 63, wv = tid >> 6;
    int v = (tid < NBLK_SCAN) ? bsum[tid] : 0;
    int sc = v;
    #pragma unroll
    for (int off = 1; off < 64; off <<= 1) {
        int u = __shfl_up(sc, off);
        if (lane >= off) sc += u;
    }
    if (lane == 63) ws[wv] = sc;
    __syncthreads();
    int wbase = 0;
    #pragma unroll
    for (int w = 0; w < 4; ++w) if (w < wv) wbase += ws[w];
    if (tid < NBLK_SCAN) bpre[tid] = wbase + sc - v;   // exclusive
}

__global__ __launch_bounds__(256) void scan3_kernel(
    const int* __restrict__ deg, const int* __restrict__ bpre,
    int* __restrict__ row_start, int* __restrict__ cursor)
{
    __shared__ int ws[4];
    int tid = threadIdx.x, lane = tid & 63, wv = tid >> 6;
    int i = blockIdx.x * 256 + tid;
    int v = (i < N_NODES) ? deg[i] : 0;
    int sc = v;
    #pragma unroll
    for (int off = 1; off < 64; off <<= 1) {
        int u = __shfl_up(sc, off);
        if (lane >= off) sc += u;
    }
    if (lane == 63) ws[wv] = sc;
    __syncthreads();
    int wbase = 0;
    #pragma unroll
    for (int w = 0; w < 4; ++w) if (w < wv) wbase += ws[w];
    int ex = bpre[blockIdx.x] + wbase + sc - v;
    if (i < N_NODES) { row_start[i] = ex; cursor[i] = ex; }
}

// ---------------- scatter edge ids into CSR slots ----------------
__global__ __launch_bounds__(256) void scatter_kernel(
    const int* __restrict__ dst, int* __restrict__ cursor, int* __restrict__ csr)
{
    int e = blockIdx.x * 256 + threadIdx.x;
    if (e < N_EDGES) {
        int pos = atomicAdd(&cursor[dst[e]], 1);
        csr[pos] = e;
    }
}

// ---------------- aggregation: one wave per node, 4-edge batched pipeline ----------------
__global__ __launch_bounds__(256) void agg_kernel(
    const float* __restrict__ P1, const float* __restrict__ P2,
    const float* __restrict__ ef, const float* __restrict__ Wpre,
    const int* __restrict__ src, const int* __restrict__ csr,
    const int* __restrict__ row_start, const int* __restrict__ deg,
    float* __restrict__ agg)
{
    int tid = threadIdx.x;
    int lane = tid & 63;

    float wef[16];
    #pragma unroll
    for (int f = 0; f < 16; ++f) wef[f] = Wpre[(128 + f) * 64 + lane];

    int n = rfl(blockIdx.x * 4 + (tid >> 6));
    if (n >= N_NODES) return;
    int rs = rfl(row_start[n]);
    int dg = rfl(deg[n]);
    size_t obase = (size_t)n * AGG_F + lane;

    if (dg == 0) {
        agg[obase] = 0.f; agg[obase + 64] = 0.f;
        agg[obase + 128] = 0.f; agg[obase + 192] = 0.f;
        return;
    }

    float p2n = P2[(size_t)n * IN_F + lane];
    float sum = 0.f, ssq = 0.f;
    float mx = -__builtin_inff(), mn = __builtin_inff();

    int i0 = 0;
    // ---- 4-edge batches: all loads independent, chain amortized 4x ----
    for (; i0 + 4 <= dg; i0 += 4) {
        int ea = rfl(csr[rs + i0]);
        int eb = rfl(csr[rs + i0 + 1]);
        int ec = rfl(csr[rs + i0 + 2]);
        int ed = rfl(csr[rs + i0 + 3]);
        int sa = rfl(src[ea]);
        int sb = rfl(src[eb]);
        int sc_ = rfl(src[ec]);
        int sd_ = rfl(src[ed]);
        float pa = P1[(size_t)sa * IN_F + lane];
        float pb = P1[(size_t)sb * IN_F + lane];
        float pc = P1[(size_t)sc_ * IN_F + lane];
        float pd = P1[(size_t)sd_ * IN_F + lane];

        float qa = 0.f, qb = 0.f, qc = 0.f, qd = 0.f;
        #pragma unroll
        for (int f = 0; f < 16; ++f) {
            // uniform addresses -> s_loads into SGPRs
            qa = fmaf(ef[(size_t)ea * ED_F + f], wef[f], qa);
            qb = fmaf(ef[(size_t)eb * ED_F + f], wef[f], qb);
            qc = fmaf(ef[(size_t)ec * ED_F + f], wef[f], qc);
            qd = fmaf(ef[(size_t)ed * ED_F + f], wef[f], qd);
        }
        float xa = pa + qa, xb = pb + qb, xc = pc + qc, xd = pd + qd;
        sum += (xa + xb) + (xc + xd);
        ssq = fmaf(xa, xa, ssq); ssq = fmaf(xb, xb, ssq);
        ssq = fmaf(xc, xc, ssq); ssq = fmaf(xd, xd, ssq);
        mx = fmaxf(mx, fmaxf(fmaxf(xa, xb), fmaxf(xc, xd)));
        mn = fminf(mn, fminf(fminf(xa, xb), fminf(xc, xd)));
    }
    // ---- tail ----
    for (; i0 < dg; ++i0) {
        int e0 = rfl(csr[rs + i0]);
        int s0 = rfl(src[e0]);
        float p1 = P1[(size_t)s0 * IN_F + lane];
        float q0 = 0.f, q1 = 0.f;
        #pragma unroll
        for (int f = 0; f < 8; ++f) {
            q0 = fmaf(ef[(size_t)e0 * ED_F + 2 * f], wef[2 * f], q0);
            q1 = fmaf(ef[(size_t)e0 * ED_F + 2 * f + 1], wef[2 * f + 1], q1);
        }
        float x = p1 + q0 + q1;
        sum += x;
        ssq = fmaf(x, x, ssq);
        mx = fmaxf(mx, x);
        mn = fminf(mn, x);
    }

    float degc = (float)dg;
    float mean_x = sum / degc;
    float sd = sqrtf(fmaxf(ssq / degc - mean_x * mean_x, 0.f) + EPS_F);  // shift-invariant
    agg[obase]       = mean_x + p2n;
    agg[obase + 64]  = mx + p2n;
    agg[obase + 128] = mn + p2n;
    agg[obase + 192] = sd;
}

// ---------------- post: out = [h,agg,amp,att]@W_post + b; *snorm ----------------
constexpr int NPW = 12;                   // nodes per wave
constexpr int NPB = 4 * NPW;              // 48 nodes per block
__global__ __launch_bounds__(256) void post_kernel(
    const float* __restrict__ h, const float* __restrict__ snorm,
    const float* __restrict__ Wpost, const float* __restrict__ bpost,
    const float* __restrict__ agg, const int* __restrict__ deg,
    float* __restrict__ out)
{
    __shared__ float aggL[NPB * AGG_F];   // 48*256*4 = 49 KB -> 3 blocks/CU

    int tid = threadIdx.x;
    int lane = tid & 63;
    int wv = tid >> 6;
    int nbase = rfl(blockIdx.x * NPB + wv * NPW);

    float hr[NPW];
    #pragma unroll
    for (int t = 0; t < NPW; ++t) {
        int n = nbase + t;
        int nb = wv * NPW + t;
        if (n < N_NODES) {
            size_t ab = (size_t)n * AGG_F + lane;
            aggL[nb * AGG_F + lane]       = agg[ab];
            aggL[nb * AGG_F + 64 + lane]  = agg[ab + 64];
            aggL[nb * AGG_F + 128 + lane] = agg[ab + 128];
            aggL[nb * AGG_F + 192 + lane] = agg[ab + 192];
            hr[t] = h[(size_t)n * IN_F + lane];
        } else {
            aggL[nb * AGG_F + lane] = 0.f; aggL[nb * AGG_F + 64 + lane] = 0.f;
            aggL[nb * AGG_F + 128 + lane] = 0.f; aggL[nb * AGG_F + 192 + lane] = 0.f;
            hr[t] = 0.f;
        }
    }
    __syncthreads();

    float aArr[NPW], bArr[NPW];
    #pragma unroll
    for (int t = 0; t < NPW; ++t) {
        int n = nbase + t;
        int dg = (n < N_NODES) ? deg[n] : 0;   // scalar load (nbase uniform)
        float degc = fmaxf((float)dg, 1.f);
        float logd = logf(degc + 1.f);
        aArr[t] = logd * (1.f / AVG_D_LOG_F);
        bArr[t] = AVG_D_LOG_F / logd;
    }

    float bp = bpost[lane];
    float acc[NPW];
    #pragma unroll
    for (int t = 0; t < NPW; ++t) acc[t] = bp;

    // h part: rows 0..63 of W_post; h broadcast from registers (no LDS)
    for (int i = 0; i < IN_F; ++i) {
        float w1 = Wpost[i * OUT_F + lane];
        #pragma unroll
        for (int t = 0; t < NPW; ++t)
            acc[t] = fmaf(rl(hr[t], i), w1, acc[t]);
    }
    // agg part: rows 64..831 folded (agg/amp/att), float4 broadcast reads from LDS
    for (int k4 = 0; k4 < AGG_F; k4 += 4) {
        float w2[4], w3[4], w4[4];
        #pragma unroll
        for (int j = 0; j < 4; ++j) {
            w2[j] = Wpost[(64 + k4 + j) * OUT_F + lane];
            w3[j] = Wpost[(320 + k4 + j) * OUT_F + lane];
            w4[j] = Wpost[(576 + k4 + j) * OUT_F + lane];
        }
        #pragma unroll
        for (int t = 0; t < NPW; ++t) {
            float4 a4 = *reinterpret_cast<const float4*>(&aggL[(wv * NPW + t) * AGG_F + k4]);
            float av[4] = {a4.x, a4.y, a4.z, a4.w};
            #pragma unroll
            for (int j = 0; j < 4; ++j) {
                float wc = fmaf(aArr[t], w3[j], w2[j]);
                wc = fmaf(bArr[t], w4[j], wc);
                acc[t] = fmaf(av[j], wc, acc[t]);
            }
        }
    }

    #pragma unroll
    for (int t = 0; t < NPW; ++t) {
        int n = nbase + t;
        if (n < N_NODES)
            out[(size_t)n * OUT_F + lane] = acc[t] * snorm[n];
    }
}

extern "C" void kernel_launch(void* const* d_in, const int* in_sizes, int n_in,
                              void* d_out, int out_size, void* d_ws, size_t ws_size,
                              hipStream_t stream) {
    const float* h     = (const float*)d_in[0];
    const float* ef    = (const float*)d_in[1];
    const float* snorm = (const float*)d_in[2];
    const float* Wpre  = (const float*)d_in[3];
    const float* bpre  = (const float*)d_in[4];
    const float* Wpost = (const float*)d_in[5];
    const float* bpost = (const float*)d_in[6];
    const int* src     = (const int*)d_in[7];
    const int* dst     = (const int*)d_in[8];
    float* out = (float*)d_out;

    char* ws = (char*)d_ws;
    size_t off = 0;
    auto alloc = [&](size_t bytes) { char* p = ws + off; off += (bytes + 255) & ~size_t(255); return p; };
    float* P1      = (float*)alloc((size_t)N_NODES * IN_F * 4);
    float* P2      = (float*)alloc((size_t)N_NODES * IN_F * 4);
    float* agg     = (float*)alloc((size_t)N_NODES * AGG_F * 4);
    int* deg       = (int*)alloc((size_t)N_NODES * 4);
    int* row_start = (int*)alloc((size_t)N_NODES * 4);
    int* cursor    = (int*)alloc((size_t)N_NODES * 4);
    int* csr       = (int*)alloc((size_t)N_EDGES * 4);
    int* bsum      = (int*)alloc((size_t)NBLK_SCAN * 4);
    int* bpre2     = (int*)alloc((size_t)NBLK_SCAN * 4);

    hipMemsetAsync(deg, 0, (size_t)N_NODES * 4, stream);
    hipLaunchKernelGGL(p12_kernel, dim3((N_NODES + 63) / 64), dim3(256), 0, stream,
                       h, Wpre, bpre, P1, P2);
    hipLaunchKernelGGL(hist_kernel, dim3((N_EDGES + 255) / 256), dim3(256), 0, stream, dst, deg);
    hipLaunchKernelGGL(scan1_kernel, dim3(NBLK_SCAN), dim3(256), 0, stream, deg, bsum);
    hipLaunchKernelGGL(scan2_kernel, dim3(1), dim3(256), 0, stream, bsum, bpre2);
    hipLaunchKernelGGL(scan3_kernel, dim3(NBLK_SCAN), dim3(256), 0, stream, deg, bpre2, row_start, cursor);
    hipLaunchKernelGGL(scatter_kernel, dim3((N_EDGES + 255) / 256), dim3(256), 0, stream,
                       dst, cursor, csr);
    hipLaunchKernelGGL(agg_kernel, dim3((N_NODES + 3) / 4), dim3(256), 0, stream,
                       P1, P2, ef, Wpre, src, csr, row_start, deg, agg);
    hipLaunchKernelGGL(post_kernel, dim3((N_NODES + NPB - 1) / NPB), dim3(256), 0, stream,
                       h, snorm, Wpost, bpost, agg, deg, out);
}

// Round 7
// 309.711 us; speedup vs baseline: 4.9643x; 1.0399x over previous
//
#include <hip/hip_runtime.h>

constexpr int N_NODES = 50000;
constexpr int N_EDGES = 800000;
constexpr int IN_F = 64;
constexpr int ED_F = 16;
constexpr int OUT_F = 64;
constexpr int AGG_F = 256;    // 4*IN
constexpr float AVG_D_LOG_F = 2.833f;
constexpr float EPS_F = 1e-5f;

__device__ __forceinline__ float rl(float v, int l) {
    return __int_as_float(__builtin_amdgcn_readlane(__float_as_int(v), l));
}
__device__ __forceinline__ int rli(int v, int l) {
    return __builtin_amdgcn_readlane(v, l);
}
__device__ __forceinline__ int rfl(int v) { return __builtin_amdgcn_readfirstlane(v); }

// ---------------- P1 = h@Wpre[0:64], P2 = h@Wpre[64:128] + b_pre ----------------
__global__ __launch_bounds__(256) void p12_kernel(
    const float* __restrict__ h, const float* __restrict__ Wpre, const float* __restrict__ bpre,
    float* __restrict__ P1, float* __restrict__ P2)
{
    __shared__ float WpL[128 * 64];   // 32 KB
    int tid = threadIdx.x;
    int lane = tid & 63;
    int wv = tid >> 6;
    for (int i = tid; i < 128 * 64; i += 256) WpL[i] = Wpre[i];
    float bj = bpre[lane];
    __syncthreads();

    int nbase = blockIdx.x * 64 + wv * 16;
    float hr[16];
    #pragma unroll
    for (int t = 0; t < 16; ++t) {
        int n = nbase + t; if (n >= N_NODES) n = N_NODES - 1;
        hr[t] = h[(size_t)n * IN_F + lane];
    }
    float p1[16], p2[16];
    #pragma unroll
    for (int t = 0; t < 16; ++t) { p1[t] = 0.f; p2[t] = bj; }

    for (int i = 0; i < 64; ++i) {
        float w1 = WpL[i * 64 + lane];
        float w2 = WpL[(64 + i) * 64 + lane];
        #pragma unroll
        for (int t = 0; t < 16; ++t) {
            float x = rl(hr[t], i);
            p1[t] = fmaf(x, w1, p1[t]);
            p2[t] = fmaf(x, w2, p2[t]);
        }
    }
    #pragma unroll
    for (int t = 0; t < 16; ++t) {
        int n = nbase + t;
        if (n < N_NODES) {
            P1[(size_t)n * IN_F + lane] = p1[t];
            P2[(size_t)n * IN_F + lane] = p2[t];
        }
    }
}

// ---------------- degree histogram ----------------
__global__ __launch_bounds__(256) void hist_kernel(const int* __restrict__ dst, int* __restrict__ deg)
{
    int e = blockIdx.x * 256 + threadIdx.x;
    if (e < N_EDGES) atomicAdd(&deg[dst[e]], 1);
}

// ---------------- 3-phase coalesced scan ----------------
constexpr int NBLK_SCAN = (N_NODES + 255) / 256;   // 196

__global__ __launch_bounds__(256) void scan1_kernel(const int* __restrict__ deg, int* __restrict__ bsum)
{
    __shared__ int ws[4];
    int tid = threadIdx.x, lane = tid & 63, wv = tid >> 6;
    int i = blockIdx.x * 256 + tid;
    int v = (i < N_NODES) ? deg[i] : 0;
    #pragma unroll
    for (int off = 32; off > 0; off >>= 1) v += __shfl_down(v, off);
    if (lane == 0) ws[wv] = v;
    __syncthreads();
    if (tid == 0) bsum[blockIdx.x] = ws[0] + ws[1] + ws[2] + ws[3];
}

__global__ __launch_bounds__(256) void scan2_kernel(const int* __restrict__ bsum, int* __restrict__ bpre)
{
    __shared__ int ws[4];
    int tid = threadIdx.x, lane = tid & 63, wv = tid >> 6;
    int v = (tid < NBLK_SCAN) ? bsum[tid] : 0;
    int sc = v;
    #pragma unroll
    for (int off = 1; off < 64; off <<= 1) {
        int u = __shfl_up(sc, off);
        if (lane >= off) sc += u;
    }
    if (lane == 63) ws[wv] = sc;
    __syncthreads();
    int wbase = 0;
    #pragma unroll
    for (int w = 0; w < 4; ++w) if (w < wv) wbase += ws[w];
    if (tid < NBLK_SCAN) bpre[tid] = wbase + sc - v;   // exclusive
}

__global__ __launch_bounds__(256) void scan3_kernel(
    const int* __restrict__ deg, const int* __restrict__ bpre,
    int* __restrict__ row_start, int* __restrict__ cursor)
{
    __shared__ int ws[4];
    int tid = threadIdx.x, lane = tid & 63, wv = tid >> 6;
    int i = blockIdx.x * 256 + tid;
    int v = (i < N_NODES) ? deg[i] : 0;
    int sc = v;
    #pragma unroll
    for (int off = 1; off < 64; off <<= 1) {
        int u = __shfl_up(sc, off);
        if (lane >= off) sc += u;
    }
    if (lane == 63) ws[wv] = sc;
    __syncthreads();
    int wbase = 0;
    #pragma unroll
    for (int w = 0; w < 4; ++w) if (w < wv) wbase += ws[w];
    int ex = bpre[blockIdx.x] + wbase + sc - v;
    if (i < N_NODES) { row_start[i] = ex; cursor[i] = ex; }
}

// ---------------- scatter edge ids into CSR slots ----------------
__global__ __launch_bounds__(256) void scatter_kernel(
    const int* __restrict__ dst, int* __restrict__ cursor, int* __restrict__ csr)
{
    int e = blockIdx.x * 256 + threadIdx.x;
    if (e < N_EDGES) {
        int pos = atomicAdd(&cursor[dst[e]], 1);
        csr[pos] = e;
    }
}

// ---------------- aggregation: one wave/node; index lists vector-loaded once;
// ---------------- chunks of 8 fully-independent gathers, broadcast via readlane
__global__ __launch_bounds__(256) void agg_kernel(
    const float* __restrict__ P1, const float* __restrict__ P2,
    const float* __restrict__ ef, const float* __restrict__ Wpre,
    const int* __restrict__ src, const int* __restrict__ csr,
    const int* __restrict__ row_start, const int* __restrict__ deg,
    float* __restrict__ agg)
{
    int tid = threadIdx.x;
    int lane = tid & 63;

    float wef[16];
    #pragma unroll
    for (int f = 0; f < 16; ++f) wef[f] = Wpre[(128 + f) * 64 + lane];

    int n = rfl(blockIdx.x * 4 + (tid >> 6));
    if (n >= N_NODES) return;
    int rs = rfl(row_start[n]);
    int dg = rfl(deg[n]);
    size_t obase = (size_t)n * AGG_F + lane;

    if (dg == 0) {
        agg[obase] = 0.f; agg[obase + 64] = 0.f;
        agg[obase + 128] = 0.f; agg[obase + 192] = 0.f;
        return;
    }

    float p2n = P2[(size_t)n * IN_F + lane];
    float sum = 0.f, ssq = 0.f;
    float mx = -__builtin_inff(), mn = __builtin_inff();

    for (int base = 0; base < dg; base += 64) {
        int cnt = dg - base; if (cnt > 64) cnt = 64;
        // one coalesced load of up to 64 edge ids, one gather of src ids
        int eid = 0, sid = 0;
        if (lane < cnt) {
            eid = csr[rs + base + lane];
            sid = src[eid];
        }
        for (int c = 0; c < cnt; c += 8) {
            float p[8], efv[8];
            // issue all 16 gathers before any use (indices clamped to valid lanes)
            #pragma unroll
            for (int k = 0; k < 8; ++k) {
                int idx = (c + k < cnt) ? (c + k) : 0;       // scalar select
                int e = rli(eid, idx);
                int s = rli(sid, idx);
                p[k]   = P1[(size_t)s * IN_F + lane];
                efv[k] = ef[(size_t)e * ED_F + (lane & 15)];
            }
            #pragma unroll
            for (int k = 0; k < 8; ++k) {
                if (c + k < cnt) {                            // wave-uniform guard
                    float q0 = 0.f, q1 = 0.f;
                    #pragma unroll
                    for (int f = 0; f < 8; ++f) {
                        q0 = fmaf(rl(efv[k], 2 * f),     wef[2 * f],     q0);
                        q1 = fmaf(rl(efv[k], 2 * f + 1), wef[2 * f + 1], q1);
                    }
                    float x = p[k] + q0 + q1;
                    sum += x;
                    ssq = fmaf(x, x, ssq);
                    mx = fmaxf(mx, x);
                    mn = fminf(mn, x);
                }
            }
        }
    }

    float degc = (float)dg;
    float mean_x = sum / degc;
    float sd = sqrtf(fmaxf(ssq / degc - mean_x * mean_x, 0.f) + EPS_F);  // shift-invariant
    agg[obase]       = mean_x + p2n;
    agg[obase + 64]  = mx + p2n;
    agg[obase + 128] = mn + p2n;
    agg[obase + 192] = sd;
}

// ---------------- post: out = [h,agg,amp,att]@W_post + b; *snorm ----------------
constexpr int NPW = 12;                   // nodes per wave
constexpr int NPB = 4 * NPW;              // 48 nodes per block
__global__ __launch_bounds__(256) void post_kernel(
    const float* __restrict__ h, const float* __restrict__ snorm,
    const float* __restrict__ Wpost, const float* __restrict__ bpost,
    const float* __restrict__ agg, const int* __restrict__ deg,
    float* __restrict__ out)
{
    __shared__ float aggL[NPB * AGG_F];   // 49 KB -> 3 blocks/CU

    int tid = threadIdx.x;
    int lane = tid & 63;
    int wv = tid >> 6;
    int nbase = rfl(blockIdx.x * NPB + wv * NPW);

    float hr[NPW];
    #pragma unroll
    for (int t = 0; t < NPW; ++t) {
        int n = nbase + t;
        int nb = wv * NPW + t;
        if (n < N_NODES) {
            size_t ab = (size_t)n * AGG_F + lane;
            aggL[nb * AGG_F + lane]       = agg[ab];
            aggL[nb * AGG_F + 64 + lane]  = agg[ab + 64];
            aggL[nb * AGG_F + 128 + lane] = agg[ab + 128];
            aggL[nb * AGG_F + 192 + lane] = agg[ab + 192];
            hr[t] = h[(size_t)n * IN_F + lane];
        } else {
            aggL[nb * AGG_F + lane] = 0.f; aggL[nb * AGG_F + 64 + lane] = 0.f;
            aggL[nb * AGG_F + 128 + lane] = 0.f; aggL[nb * AGG_F + 192 + lane] = 0.f;
            hr[t] = 0.f;
        }
    }
    __syncthreads();

    float aArr[NPW], bArr[NPW];
    #pragma unroll
    for (int t = 0; t < NPW; ++t) {
        int n = nbase + t;
        int dg = (n < N_NODES) ? deg[n] : 0;   // scalar load (nbase uniform)
        float degc = fmaxf((float)dg, 1.f);
        float logd = logf(degc + 1.f);
        aArr[t] = logd * (1.f / AVG_D_LOG_F);
        bArr[t] = AVG_D_LOG_F / logd;
    }

    float bp = bpost[lane];
    float acc[NPW];
    #pragma unroll
    for (int t = 0; t < NPW; ++t) acc[t] = bp;

    // h part: rows 0..63 of W_post; h broadcast from registers (no LDS)
    for (int i = 0; i < IN_F; ++i) {
        float w1 = Wpost[i * OUT_F + lane];
        #pragma unroll
        for (int t = 0; t < NPW; ++t)
            acc[t] = fmaf(rl(hr[t], i), w1, acc[t]);
    }
    // agg part: rows 64..831 folded (agg/amp/att), float4 broadcast reads from LDS
    for (int k4 = 0; k4 < AGG_F; k4 += 4) {
        float w2[4], w3[4], w4[4];
        #pragma unroll
        for (int j = 0; j < 4; ++j) {
            w2[j] = Wpost[(64 + k4 + j) * OUT_F + lane];
            w3[j] = Wpost[(320 + k4 + j) * OUT_F + lane];
            w4[j] = Wpost[(576 + k4 + j) * OUT_F + lane];
        }
        #pragma unroll
        for (int t = 0; t < NPW; ++t) {
            float4 a4 = *reinterpret_cast<const float4*>(&aggL[(wv * NPW + t) * AGG_F + k4]);
            float av[4] = {a4.x, a4.y, a4.z, a4.w};
            #pragma unroll
            for (int j = 0; j < 4; ++j) {
                float wc = fmaf(aArr[t], w3[j], w2[j]);
                wc = fmaf(bArr[t], w4[j], wc);
                acc[t] = fmaf(av[j], wc, acc[t]);
            }
        }
    }

    #pragma unroll
    for (int t = 0; t < NPW; ++t) {
        int n = nbase + t;
        if (n < N_NODES)
            out[(size_t)n * OUT_F + lane] = acc[t] * snorm[n];
    }
}

extern "C" void kernel_launch(void* const* d_in, const int* in_sizes, int n_in,
                              void* d_out, int out_size, void* d_ws, size_t ws_size,
                              hipStream_t stream) {
    const float* h     = (const float*)d_in[0];
    const float* ef    = (const float*)d_in[1];
    const float* snorm = (const float*)d_in[2];
    const float* Wpre  = (const float*)d_in[3];
    const float* bpre  = (const float*)d_in[4];
    const float* Wpost = (const float*)d_in[5];
    const float* bpost = (const float*)d_in[6];
    const int* src     = (const int*)d_in[7];
    const int* dst     = (const int*)d_in[8];
    float* out = (float*)d_out;

    char* ws = (char*)d_ws;
    size_t off = 0;
    auto alloc = [&](size_t bytes) { char* p = ws + off; off += (bytes + 255) & ~size_t(255); return p; };
    float* P1      = (float*)alloc((size_t)N_NODES * IN_F * 4);
    float* P2      = (float*)alloc((size_t)N_NODES * IN_F * 4);
    float* agg     = (float*)alloc((size_t)N_NODES * AGG_F * 4);
    int* deg       = (int*)alloc((size_t)N_NODES * 4);
    int* row_start = (int*)alloc((size_t)N_NODES * 4);
    int* cursor    = (int*)alloc((size_t)N_NODES * 4);
    int* csr       = (int*)alloc((size_t)N_EDGES * 4);
    int* bsum      = (int*)alloc((size_t)NBLK_SCAN * 4);
    int* bpre2     = (int*)alloc((size_t)NBLK_SCAN * 4);

    hipMemsetAsync(deg, 0, (size_t)N_NODES * 4, stream);
    hipLaunchKernelGGL(p12_kernel, dim3((N_NODES + 63) / 64), dim3(256), 0, stream,
                       h, Wpre, bpre, P1, P2);
    hipLaunchKernelGGL(hist_kernel, dim3((N_EDGES + 255) / 256), dim3(256), 0, stream, dst, deg);
    hipLaunchKernelGGL(scan1_kernel, dim3(NBLK_SCAN), dim3(256), 0, stream, deg, bsum);
    hipLaunchKernelGGL(scan2_kernel, dim3(1), dim3(256), 0, stream, bsum, bpre2);
    hipLaunchKernelGGL(scan3_kernel, dim3(NBLK_SCAN), dim3(256), 0, stream, deg, bpre2, row_start, cursor);
    hipLaunchKernelGGL(scatter_kernel, dim3((N_EDGES + 255) / 256), dim3(256), 0, stream,
                       dst, cursor, csr);
    hipLaunchKernelGGL(agg_kernel, dim3((N_NODES + 3) / 4), dim3(256), 0, stream,
                       P1, P2, ef, Wpre, src, csr, row_start, deg, agg);
    hipLaunchKernelGGL(post_kernel, dim3((N_NODES + NPB - 1) / NPB), dim3(256), 0, stream,
                       h, snorm, Wpost, bpost, agg, deg, out);
}

// Round 8
// 270.051 us; speedup vs baseline: 5.6933x; 1.1469x over previous
//
#include <hip/hip_runtime.h>

constexpr int N_NODES = 50000;
constexpr int N_EDGES = 800000;
constexpr int IN_F = 64;
constexpr int ED_F = 16;
constexpr int OUT_F = 64;
constexpr int AGG_F = 256;    // 4*IN
constexpr int KTOT = 832;     // 13*64
constexpr float AVG_D_LOG_F = 2.833f;
constexpr float EPS_F = 1e-5f;

typedef __attribute__((ext_vector_type(8))) short short8;
typedef __attribute__((ext_vector_type(4))) float f32x4;

__device__ __forceinline__ float rl(float v, int l) {
    return __int_as_float(__builtin_amdgcn_readlane(__float_as_int(v), l));
}
__device__ __forceinline__ int rli(int v, int l) {
    return __builtin_amdgcn_readlane(v, l);
}
__device__ __forceinline__ int rfl(int v) { return __builtin_amdgcn_readfirstlane(v); }
__device__ __forceinline__ unsigned short f2bf(float f) {   // RNE f32->bf16
    unsigned u = __float_as_uint(f);
    unsigned r = (u + 0x7FFFu + ((u >> 16) & 1u)) >> 16;
    return (unsigned short)r;
}

// ---------------- P1 = h@Wpre[0:64], P2 = h@Wpre[64:128] + b_pre ----------------
__global__ __launch_bounds__(256) void p12_kernel(
    const float* __restrict__ h, const float* __restrict__ Wpre, const float* __restrict__ bpre,
    float* __restrict__ P1, float* __restrict__ P2)
{
    __shared__ float WpL[128 * 64];   // 32 KB
    int tid = threadIdx.x;
    int lane = tid & 63;
    int wv = tid >> 6;
    for (int i = tid; i < 128 * 64; i += 256) WpL[i] = Wpre[i];
    float bj = bpre[lane];
    __syncthreads();

    int nbase = blockIdx.x * 64 + wv * 16;
    float hr[16];
    #pragma unroll
    for (int t = 0; t < 16; ++t) {
        int n = nbase + t; if (n >= N_NODES) n = N_NODES - 1;
        hr[t] = h[(size_t)n * IN_F + lane];
    }
    float p1[16], p2[16];
    #pragma unroll
    for (int t = 0; t < 16; ++t) { p1[t] = 0.f; p2[t] = bj; }

    for (int i = 0; i < 64; ++i) {
        float w1 = WpL[i * 64 + lane];
        float w2 = WpL[(64 + i) * 64 + lane];
        #pragma unroll
        for (int t = 0; t < 16; ++t) {
            float x = rl(hr[t], i);
            p1[t] = fmaf(x, w1, p1[t]);
            p2[t] = fmaf(x, w2, p2[t]);
        }
    }
    #pragma unroll
    for (int t = 0; t < 16; ++t) {
        int n = nbase + t;
        if (n < N_NODES) {
            P1[(size_t)n * IN_F + lane] = p1[t];
            P2[(size_t)n * IN_F + lane] = p2[t];
        }
    }
}

// ---------------- degree histogram ----------------
__global__ __launch_bounds__(256) void hist_kernel(const int* __restrict__ dst, int* __restrict__ deg)
{
    int e = blockIdx.x * 256 + threadIdx.x;
    if (e < N_EDGES) atomicAdd(&deg[dst[e]], 1);
}

// ---------------- 3-phase coalesced scan ----------------
constexpr int NBLK_SCAN = (N_NODES + 255) / 256;   // 196

__global__ __launch_bounds__(256) void scan1_kernel(const int* __restrict__ deg, int* __restrict__ bsum)
{
    __shared__ int ws[4];
    int tid = threadIdx.x, lane = tid & 63, wv = tid >> 6;
    int i = blockIdx.x * 256 + tid;
    int v = (i < N_NODES) ? deg[i] : 0;
    #pragma unroll
    for (int off = 32; off > 0; off >>= 1) v += __shfl_down(v, off);
    if (lane == 0) ws[wv] = v;
    __syncthreads();
    if (tid == 0) bsum[blockIdx.x] = ws[0] + ws[1] + ws[2] + ws[3];
}

__global__ __launch_bounds__(256) void scan2_kernel(const int* __restrict__ bsum, int* __restrict__ bpre)
{
    __shared__ int ws[4];
    int tid = threadIdx.x, lane = tid & 63, wv = tid >> 6;
    int v = (tid < NBLK_SCAN) ? bsum[tid] : 0;
    int sc = v;
    #pragma unroll
    for (int off = 1; off < 64; off <<= 1) {
        int u = __shfl_up(sc, off);
        if (lane >= off) sc += u;
    }
    if (lane == 63) ws[wv] = sc;
    __syncthreads();
    int wbase = 0;
    #pragma unroll
    for (int w = 0; w < 4; ++w) if (w < wv) wbase += ws[w];
    if (tid < NBLK_SCAN) bpre[tid] = wbase + sc - v;   // exclusive
}

__global__ __launch_bounds__(256) void scan3_kernel(
    const int* __restrict__ deg, const int* __restrict__ bpre,
    int* __restrict__ row_start, int* __restrict__ cursor)
{
    __shared__ int ws[4];
    int tid = threadIdx.x, lane = tid & 63, wv = tid >> 6;
    int i = blockIdx.x * 256 + tid;
    int v = (i < N_NODES) ? deg[i] : 0;
    int sc = v;
    #pragma unroll
    for (int off = 1; off < 64; off <<= 1) {
        int u = __shfl_up(sc, off);
        if (lane >= off) sc += u;
    }
    if (lane == 63) ws[wv] = sc;
    __syncthreads();
    int wbase = 0;
    #pragma unroll
    for (int w = 0; w < 4; ++w) if (w < wv) wbase += ws[w];
    int ex = bpre[blockIdx.x] + wbase + sc - v;
    if (i < N_NODES) { row_start[i] = ex; cursor[i] = ex; }
}

// ---------------- scatter edge ids into CSR slots ----------------
__global__ __launch_bounds__(256) void scatter_kernel(
    const int* __restrict__ dst, int* __restrict__ cursor, int* __restrict__ csr)
{
    int e = blockIdx.x * 256 + threadIdx.x;
    if (e < N_EDGES) {
        int pos = atomicAdd(&cursor[dst[e]], 1);
        csr[pos] = e;
    }
}

// ---------------- aggregation (unchanged from R7) ----------------
__global__ __launch_bounds__(256) void agg_kernel(
    const float* __restrict__ P1, const float* __restrict__ P2,
    const float* __restrict__ ef, const float* __restrict__ Wpre,
    const int* __restrict__ src, const int* __restrict__ csr,
    const int* __restrict__ row_start, const int* __restrict__ deg,
    float* __restrict__ agg)
{
    int tid = threadIdx.x;
    int lane = tid & 63;

    float wef[16];
    #pragma unroll
    for (int f = 0; f < 16; ++f) wef[f] = Wpre[(128 + f) * 64 + lane];

    int n = rfl(blockIdx.x * 4 + (tid >> 6));
    if (n >= N_NODES) return;
    int rs = rfl(row_start[n]);
    int dg = rfl(deg[n]);
    size_t obase = (size_t)n * AGG_F + lane;

    if (dg == 0) {
        agg[obase] = 0.f; agg[obase + 64] = 0.f;
        agg[obase + 128] = 0.f; agg[obase + 192] = 0.f;
        return;
    }

    float p2n = P2[(size_t)n * IN_F + lane];
    float sum = 0.f, ssq = 0.f;
    float mx = -__builtin_inff(), mn = __builtin_inff();

    for (int base = 0; base < dg; base += 64) {
        int cnt = dg - base; if (cnt > 64) cnt = 64;
        int eid = 0, sid = 0;
        if (lane < cnt) {
            eid = csr[rs + base + lane];
            sid = src[eid];
        }
        for (int c = 0; c < cnt; c += 8) {
            float p[8], efv[8];
            #pragma unroll
            for (int k = 0; k < 8; ++k) {
                int idx = (c + k < cnt) ? (c + k) : 0;
                int e = rli(eid, idx);
                int s = rli(sid, idx);
                p[k]   = P1[(size_t)s * IN_F + lane];
                efv[k] = ef[(size_t)e * ED_F + (lane & 15)];
            }
            #pragma unroll
            for (int k = 0; k < 8; ++k) {
                if (c + k < cnt) {
                    float q0 = 0.f, q1 = 0.f;
                    #pragma unroll
                    for (int f = 0; f < 8; ++f) {
                        q0 = fmaf(rl(efv[k], 2 * f),     wef[2 * f],     q0);
                        q1 = fmaf(rl(efv[k], 2 * f + 1), wef[2 * f + 1], q1);
                    }
                    float x = p[k] + q0 + q1;
                    sum += x;
                    ssq = fmaf(x, x, ssq);
                    mx = fmaxf(mx, x);
                    mn = fminf(mn, x);
                }
            }
        }
    }

    float degc = (float)dg;
    float mean_x = sum / degc;
    float sd = sqrtf(fmaxf(ssq / degc - mean_x * mean_x, 0.f) + EPS_F);
    agg[obase]       = mean_x + p2n;
    agg[obase + 64]  = mx + p2n;
    agg[obase + 128] = mn + p2n;
    agg[obase + 192] = sd;
}

// ---------------- W_post -> bf16, transposed: WT[n][k], n<64, k<832 ----------------
__global__ __launch_bounds__(256) void wprep_kernel(
    const float* __restrict__ Wpost, unsigned short* __restrict__ WT)
{
    int i = blockIdx.x * 256 + threadIdx.x;
    if (i < OUT_F * KTOT) {
        int n = i / KTOT, k = i % KTOT;
        WT[i] = f2bf(Wpost[(size_t)k * OUT_F + n]);
    }
}

// ---------------- MFMA post: out = hcat_bf16 @ Wpost_bf16 + b; *snorm ----------------
// hcat[n][k]: k<64 -> h ; 64..319 -> agg ; 320..575 -> agg*a ; 576..831 -> agg*b
constexpr int LDA = 72;   // shorts per row (144 B, padded: bank-rotates rows)
__global__ __launch_bounds__(256) void postmm_kernel(
    const float* __restrict__ h, const float* __restrict__ snorm,
    const unsigned short* __restrict__ WT, const float* __restrict__ bpost,
    const float* __restrict__ aggb, const int* __restrict__ deg,
    float* __restrict__ out)
{
    __shared__ short A_lds[64 * LDA];   // 9.2 KB

    int tid = threadIdx.x;
    int lane = tid & 63;
    int w = tid >> 6;
    int g = lane >> 4;
    int n0 = blockIdx.x * 64;

    // staging role: thread t covers row r = t>>2, cols cgf..cgf+15 of the 64-wide chunk
    int r = tid >> 2;
    int cgf = (tid & 3) * 16;
    bool vrow = (n0 + r) < N_NODES;

    // per-row amplification scalers
    float aR, bR;
    {
        int dg = vrow ? deg[n0 + r] : 0;
        float degc = fmaxf((float)dg, 1.f);
        float logd = logf(degc + 1.f);
        aR = logd * (1.f / AVG_D_LOG_F);
        bR = AVG_D_LOG_F / logd;
    }

    f32x4 acc[4];
    #pragma unroll
    for (int j = 0; j < 4; ++j) acc[j] = (f32x4)0.f;

    for (int c = 0; c < 13; ++c) {
        // ---- load + convert staging data into registers ----
        unsigned short u[16];
        if (vrow) {
            const float* srow;
            float scl = 1.f;
            if (c == 0) {
                srow = h + (size_t)(n0 + r) * IN_F + cgf;
            } else {
                int q0 = ((c - 1) & 3) * 64;
                srow = aggb + (size_t)(n0 + r) * AGG_F + q0 + cgf;
                int sec = (c - 1) >> 2;
                scl = (sec == 0) ? 1.f : ((sec == 1) ? aR : bR);
            }
            #pragma unroll
            for (int q = 0; q < 4; ++q) {
                float4 v = *reinterpret_cast<const float4*>(srow + 4 * q);
                u[4 * q + 0] = f2bf(v.x * scl);
                u[4 * q + 1] = f2bf(v.y * scl);
                u[4 * q + 2] = f2bf(v.z * scl);
                u[4 * q + 3] = f2bf(v.w * scl);
            }
        } else {
            #pragma unroll
            for (int q = 0; q < 16; ++q) u[q] = 0;
        }
        __syncthreads();   // previous chunk's compute done
        *reinterpret_cast<short8*>(&A_lds[r * LDA + cgf])     = *reinterpret_cast<short8*>(&u[0]);
        *reinterpret_cast<short8*>(&A_lds[r * LDA + cgf + 8]) = *reinterpret_cast<short8*>(&u[8]);
        __syncthreads();   // staging visible

        // ---- MFMA over this 64-k chunk (2 k-steps of 32) ----
        int arow = w * 16 + (lane & 15);
        #pragma unroll
        for (int s = 0; s < 2; ++s) {
            short8 af = *reinterpret_cast<const short8*>(&A_lds[arow * LDA + s * 32 + g * 8]);
            int kk = c * 64 + s * 32 + g * 8;
            #pragma unroll
            for (int j = 0; j < 4; ++j) {
                short8 bf = *reinterpret_cast<const short8*>(&WT[(size_t)(j * 16 + (lane & 15)) * KTOT + kk]);
                acc[j] = __builtin_amdgcn_mfma_f32_16x16x32_bf16(af, bf, acc[j], 0, 0, 0);
            }
        }
    }

    // ---- epilogue: D col=lane&15, row=(lane>>4)*4+reg (m89-verified) ----
    float bp[4];
    #pragma unroll
    for (int j = 0; j < 4; ++j) bp[j] = bpost[j * 16 + (lane & 15)];

    #pragma unroll
    for (int rr = 0; rr < 4; ++rr) {
        int node = n0 + w * 16 + g * 4 + rr;
        if (node < N_NODES) {
            float sn = snorm[node];
            #pragma unroll
            for (int j = 0; j < 4; ++j) {
                out[(size_t)node * OUT_F + j * 16 + (lane & 15)] = (acc[j][rr] + bp[j]) * sn;
            }
        }
    }
}

extern "C" void kernel_launch(void* const* d_in, const int* in_sizes, int n_in,
                              void* d_out, int out_size, void* d_ws, size_t ws_size,
                              hipStream_t stream) {
    const float* h     = (const float*)d_in[0];
    const float* ef    = (const float*)d_in[1];
    const float* snorm = (const float*)d_in[2];
    const float* Wpre  = (const float*)d_in[3];
    const float* bpre  = (const float*)d_in[4];
    const float* Wpost = (const float*)d_in[5];
    const float* bpost = (const float*)d_in[6];
    const int* src     = (const int*)d_in[7];
    const int* dst     = (const int*)d_in[8];
    float* out = (float*)d_out;

    char* ws = (char*)d_ws;
    size_t off = 0;
    auto alloc = [&](size_t bytes) { char* p = ws + off; off += (bytes + 255) & ~size_t(255); return p; };
    float* P1      = (float*)alloc((size_t)N_NODES * IN_F * 4);
    float* P2      = (float*)alloc((size_t)N_NODES * IN_F * 4);
    float* agg     = (float*)alloc((size_t)N_NODES * AGG_F * 4);
    int* deg       = (int*)alloc((size_t)N_NODES * 4);
    int* row_start = (int*)alloc((size_t)N_NODES * 4);
    int* cursor    = (int*)alloc((size_t)N_NODES * 4);
    int* csr       = (int*)alloc((size_t)N_EDGES * 4);
    int* bsum      = (int*)alloc((size_t)NBLK_SCAN * 4);
    int* bpre2     = (int*)alloc((size_t)NBLK_SCAN * 4);
    unsigned short* WT = (unsigned short*)alloc((size_t)OUT_F * KTOT * 2);   // 106 KB

    hipMemsetAsync(deg, 0, (size_t)N_NODES * 4, stream);
    hipLaunchKernelGGL(p12_kernel, dim3((N_NODES + 63) / 64), dim3(256), 0, stream,
                       h, Wpre, bpre, P1, P2);
    hipLaunchKernelGGL(hist_kernel, dim3((N_EDGES + 255) / 256), dim3(256), 0, stream, dst, deg);
    hipLaunchKernelGGL(scan1_kernel, dim3(NBLK_SCAN), dim3(256), 0, stream, deg, bsum);
    hipLaunchKernelGGL(scan2_kernel, dim3(1), dim3(256), 0, stream, bsum, bpre2);
    hipLaunchKernelGGL(scan3_kernel, dim3(NBLK_SCAN), dim3(256), 0, stream, deg, bpre2, row_start, cursor);
    hipLaunchKernelGGL(scatter_kernel, dim3((N_EDGES + 255) / 256), dim3(256), 0, stream,
                       dst, cursor, csr);
    hipLaunchKernelGGL(wprep_kernel, dim3((OUT_F * KTOT + 255) / 256), dim3(256), 0, stream,
                       Wpost, WT);
    hipLaunchKernelGGL(agg_kernel, dim3((N_NODES + 3) / 4), dim3(256), 0, stream,
                       P1, P2, ef, Wpre, src, csr, row_start, deg, agg);
    hipLaunchKernelGGL(postmm_kernel, dim3((N_NODES + 63) / 64), dim3(256), 0, stream,
                       h, snorm, WT, bpost, agg, deg, out);
}

// Round 9
// 260.599 us; speedup vs baseline: 5.8998x; 1.0363x over previous
//
#include <hip/hip_runtime.h>

constexpr int N_NODES = 50000;
constexpr int N_EDGES = 800000;
constexpr int IN_F = 64;
constexpr int ED_F = 16;
constexpr int OUT_F = 64;
constexpr int AGG_F = 256;    // 4*IN
constexpr int KTOT = 832;     // 13*64
constexpr float AVG_D_LOG_F = 2.833f;
constexpr float EPS_F = 1e-5f;

typedef __attribute__((ext_vector_type(8))) short short8;
typedef __attribute__((ext_vector_type(4))) float f32x4;

__device__ __forceinline__ float rl(float v, int l) {
    return __int_as_float(__builtin_amdgcn_readlane(__float_as_int(v), l));
}
__device__ __forceinline__ int rfl(int v) { return __builtin_amdgcn_readfirstlane(v); }
__device__ __forceinline__ unsigned short f2bf(float f) {   // RNE f32->bf16
    unsigned u = __float_as_uint(f);
    unsigned r = (u + 0x7FFFu + ((u >> 16) & 1u)) >> 16;
    return (unsigned short)r;
}

// ---------------- P1(bf16) = h@Wpre[0:64], P2(f32) = h@Wpre[64:128] + b_pre ----------------
__global__ __launch_bounds__(256) void p12_kernel(
    const float* __restrict__ h, const float* __restrict__ Wpre, const float* __restrict__ bpre,
    unsigned short* __restrict__ P1b, float* __restrict__ P2)
{
    __shared__ float WpL[128 * 64];   // 32 KB
    int tid = threadIdx.x;
    int lane = tid & 63;
    int wv = tid >> 6;
    for (int i = tid; i < 128 * 64; i += 256) WpL[i] = Wpre[i];
    float bj = bpre[lane];
    __syncthreads();

    int nbase = blockIdx.x * 64 + wv * 16;
    float hr[16];
    #pragma unroll
    for (int t = 0; t < 16; ++t) {
        int n = nbase + t; if (n >= N_NODES) n = N_NODES - 1;
        hr[t] = h[(size_t)n * IN_F + lane];
    }
    float p1[16], p2[16];
    #pragma unroll
    for (int t = 0; t < 16; ++t) { p1[t] = 0.f; p2[t] = bj; }

    for (int i = 0; i < 64; ++i) {
        float w1 = WpL[i * 64 + lane];
        float w2 = WpL[(64 + i) * 64 + lane];
        #pragma unroll
        for (int t = 0; t < 16; ++t) {
            float x = rl(hr[t], i);
            p1[t] = fmaf(x, w1, p1[t]);
            p2[t] = fmaf(x, w2, p2[t]);
        }
    }
    #pragma unroll
    for (int t = 0; t < 16; ++t) {
        int n = nbase + t;
        if (n < N_NODES) {
            P1b[(size_t)n * IN_F + lane] = f2bf(p1[t]);
            P2[(size_t)n * IN_F + lane] = p2[t];
        }
    }
}

// ---------------- degree histogram ----------------
__global__ __launch_bounds__(256) void hist_kernel(const int* __restrict__ dst, int* __restrict__ deg)
{
    int e = blockIdx.x * 256 + threadIdx.x;
    if (e < N_EDGES) atomicAdd(&deg[dst[e]], 1);
}

// ---------------- 3-phase coalesced scan ----------------
constexpr int NBLK_SCAN = (N_NODES + 255) / 256;   // 196

__global__ __launch_bounds__(256) void scan1_kernel(const int* __restrict__ deg, int* __restrict__ bsum)
{
    __shared__ int ws[4];
    int tid = threadIdx.x, lane = tid & 63, wv = tid >> 6;
    int i = blockIdx.x * 256 + tid;
    int v = (i < N_NODES) ? deg[i] : 0;
    #pragma unroll
    for (int off = 32; off > 0; off >>= 1) v += __shfl_down(v, off);
    if (lane == 0) ws[wv] = v;
    __syncthreads();
    if (tid == 0) bsum[blockIdx.x] = ws[0] + ws[1] + ws[2] + ws[3];
}

__global__ __launch_bounds__(256) void scan2_kernel(const int* __restrict__ bsum, int* __restrict__ bpre)
{
    __shared__ int ws[4];
    int tid = threadIdx.x, lane = tid & 63, wv = tid >> 6;
    int v = (tid < NBLK_SCAN) ? bsum[tid] : 0;
    int sc = v;
    #pragma unroll
    for (int off = 1; off < 64; off <<= 1) {
        int u = __shfl_up(sc, off);
        if (lane >= off) sc += u;
    }
    if (lane == 63) ws[wv] = sc;
    __syncthreads();
    int wbase = 0;
    #pragma unroll
    for (int w = 0; w < 4; ++w) if (w < wv) wbase += ws[w];
    if (tid < NBLK_SCAN) bpre[tid] = wbase + sc - v;   // exclusive
}

__global__ __launch_bounds__(256) void scan3_kernel(
    const int* __restrict__ deg, const int* __restrict__ bpre,
    int* __restrict__ row_start, int* __restrict__ cursor)
{
    __shared__ int ws[4];
    int tid = threadIdx.x, lane = tid & 63, wv = tid >> 6;
    int i = blockIdx.x * 256 + tid;
    int v = (i < N_NODES) ? deg[i] : 0;
    int sc = v;
    #pragma unroll
    for (int off = 1; off < 64; off <<= 1) {
        int u = __shfl_up(sc, off);
        if (lane >= off) sc += u;
    }
    if (lane == 63) ws[wv] = sc;
    __syncthreads();
    int wbase = 0;
    #pragma unroll
    for (int w = 0; w < 4; ++w) if (w < wv) wbase += ws[w];
    int ex = bpre[blockIdx.x] + wbase + sc - v;
    if (i < N_NODES) { row_start[i] = ex; cursor[i] = ex; }
}

// ---------------- scatter edge ids into CSR slots ----------------
__global__ __launch_bounds__(256) void scatter_kernel(
    const int* __restrict__ dst, int* __restrict__ cursor, int* __restrict__ csr)
{
    int e = blockIdx.x * 256 + threadIdx.x;
    if (e < N_EDGES) {
        int pos = atomicAdd(&cursor[dst[e]], 1);
        csr[pos] = e;
    }
}

// ---------------- W_post -> bf16 transposed WT[n][k]; Wef -> bf16 transposed WefT[n][k] ----------------
__global__ __launch_bounds__(256) void wprep_kernel(
    const float* __restrict__ Wpost, const float* __restrict__ Wpre,
    unsigned short* __restrict__ WT, unsigned short* __restrict__ WefT)
{
    int i = blockIdx.x * 256 + threadIdx.x;
    if (i < OUT_F * KTOT) {
        int n = i / KTOT, k = i % KTOT;
        WT[i] = f2bf(Wpost[(size_t)k * OUT_F + n]);
    }
    if (i < 64 * 16) {
        int n = i >> 4, k = i & 15;
        WefT[i] = f2bf(Wpre[(128 + k) * 64 + n]);
    }
}

// ---------------- aggregation via MFMA: one wave per node ----------------
// X[e][f] = P1[src_e] (via identity-B MFMA) + ef_e @ Wef (k=16 padded MFMA)
// stats accumulated in C-layout (col=lane&15 per ct-tile, row=(lane>>4)*4+rr),
// reduced with shfl_xor(16,32) butterfly, remapped to feature=lane by 3 selects.
__global__ __launch_bounds__(256) void aggmm_kernel(
    const unsigned short* __restrict__ P1b, const float* __restrict__ P2,
    const float* __restrict__ ef, const unsigned short* __restrict__ WefT,
    const int* __restrict__ src, const int* __restrict__ csr,
    const int* __restrict__ row_start, const int* __restrict__ deg,
    float* __restrict__ agg)
{
    int tid = threadIdx.x;
    int lane = tid & 63;
    int lg = lane >> 4;        // lane group 0..3
    int li = lane & 15;

    // --- B fragments (built once per wave) ---
    // identity: B_I[ct]: 1.0 where k_local == (ct&1)*16 + li
    short8 bI[4];
    #pragma unroll
    for (int ct = 0; ct < 4; ++ct) {
        short8 b = {};
        #pragma unroll
        for (int j = 0; j < 8; ++j) {
            int k_local = (lg << 3) + j;
            b[j] = (k_local == ((ct & 1) << 4) + li) ? (short)0x3F80 : (short)0;
        }
        bI[ct] = b;
    }
    // Wef: B_ef[ct]: col = ct*16+li, k = lg*8+j (k>=16 -> 0 i.e. lanes >=32)
    short8 bE[4];
    #pragma unroll
    for (int ct = 0; ct < 4; ++ct) {
        short8 b = {};
        if (lane < 32)
            b = *reinterpret_cast<const short8*>(WefT + (size_t)(ct * 16 + li) * 16 + (lg << 3));
        bE[ct] = b;
    }

    int n = rfl(blockIdx.x * 4 + (tid >> 6));
    if (n >= N_NODES) return;
    int rs = rfl(row_start[n]);
    int dg = rfl(deg[n]);
    size_t obase = (size_t)n * AGG_F + lane;

    if (dg == 0) {
        agg[obase] = 0.f; agg[obase + 64] = 0.f;
        agg[obase + 128] = 0.f; agg[obase + 192] = 0.f;
        return;
    }

    float p2n = P2[(size_t)n * IN_F + lane];
    const float NINF = -__builtin_inff(), PINF = __builtin_inff();
    float sm[4] = {0.f, 0.f, 0.f, 0.f};
    float sq[4] = {0.f, 0.f, 0.f, 0.f};
    float mx[4] = {NINF, NINF, NINF, NINF};
    float mn[4] = {PINF, PINF, PINF, PINF};

    for (int base = 0; base < dg; base += 64) {
        int cnt = dg - base; if (cnt > 64) cnt = 64;
        int eid = 0, sid = 0;
        if (lane < cnt) {
            eid = csr[rs + base + lane];
            sid = src[eid];
        }
        int nrt = (cnt + 15) >> 4;
        for (int rt = 0; rt < nrt; ++rt) {
            int srcidx = rt * 16 + li;
            int s_l = __shfl(sid, srcidx);
            int e_l = __shfl(eid, srcidx);
            // A fragments: row = li (edge), k = lg*8+j
            short8 aP0 = *reinterpret_cast<const short8*>(P1b + (size_t)s_l * IN_F + (lg << 3));
            short8 aP1 = *reinterpret_cast<const short8*>(P1b + (size_t)s_l * IN_F + 32 + (lg << 3));
            short8 aE = {};
            if (lane < 32) {
                const float* er = ef + (size_t)e_l * ED_F + (lg << 3);
                float4 v0 = *reinterpret_cast<const float4*>(er);
                float4 v1 = *reinterpret_cast<const float4*>(er + 4);
                aE[0] = (short)f2bf(v0.x); aE[1] = (short)f2bf(v0.y);
                aE[2] = (short)f2bf(v0.z); aE[3] = (short)f2bf(v0.w);
                aE[4] = (short)f2bf(v1.x); aE[5] = (short)f2bf(v1.y);
                aE[6] = (short)f2bf(v1.z); aE[7] = (short)f2bf(v1.w);
            }

            f32x4 c0 = {0.f,0.f,0.f,0.f}, c1 = {0.f,0.f,0.f,0.f};
            f32x4 c2 = {0.f,0.f,0.f,0.f}, c3 = {0.f,0.f,0.f,0.f};
            // P1 pass-through: ct 0,1 use k 0..31 (aP0); ct 2,3 use k 32..63 (aP1)
            c0 = __builtin_amdgcn_mfma_f32_16x16x32_bf16(aP0, bI[0], c0, 0, 0, 0);
            c1 = __builtin_amdgcn_mfma_f32_16x16x32_bf16(aP0, bI[1], c1, 0, 0, 0);
            c2 = __builtin_amdgcn_mfma_f32_16x16x32_bf16(aP1, bI[2], c2, 0, 0, 0);
            c3 = __builtin_amdgcn_mfma_f32_16x16x32_bf16(aP1, bI[3], c3, 0, 0, 0);
            // ef @ Wef
            c0 = __builtin_amdgcn_mfma_f32_16x16x32_bf16(aE, bE[0], c0, 0, 0, 0);
            c1 = __builtin_amdgcn_mfma_f32_16x16x32_bf16(aE, bE[1], c1, 0, 0, 0);
            c2 = __builtin_amdgcn_mfma_f32_16x16x32_bf16(aE, bE[2], c2, 0, 0, 0);
            c3 = __builtin_amdgcn_mfma_f32_16x16x32_bf16(aE, bE[3], c3, 0, 0, 0);

            // stats in C-layout; edge row = rt*16 + lg*4 + rr
            int rowb = rt * 16 + (lg << 2);
            #pragma unroll
            for (int rr = 0; rr < 4; ++rr) {
                bool v = (rowb + rr) < cnt;
                float x0 = c0[rr], x1 = c1[rr], x2 = c2[rr], x3 = c3[rr];
                float z0 = v ? x0 : 0.f, z1 = v ? x1 : 0.f, z2 = v ? x2 : 0.f, z3 = v ? x3 : 0.f;
                sm[0] += z0; sm[1] += z1; sm[2] += z2; sm[3] += z3;
                sq[0] = fmaf(z0, z0, sq[0]); sq[1] = fmaf(z1, z1, sq[1]);
                sq[2] = fmaf(z2, z2, sq[2]); sq[3] = fmaf(z3, z3, sq[3]);
                mx[0] = fmaxf(mx[0], v ? x0 : NINF); mx[1] = fmaxf(mx[1], v ? x1 : NINF);
                mx[2] = fmaxf(mx[2], v ? x2 : NINF); mx[3] = fmaxf(mx[3], v ? x3 : NINF);
                mn[0] = fminf(mn[0], v ? x0 : PINF); mn[1] = fminf(mn[1], v ? x1 : PINF);
                mn[2] = fminf(mn[2], v ? x2 : PINF); mn[3] = fminf(mn[3], v ? x3 : PINF);
            }
        }
    }

    // butterfly over lane groups (same feature cols live at lane^16, lane^32)
    #pragma unroll
    for (int ct = 0; ct < 4; ++ct) {
        #pragma unroll
        for (int off = 16; off <= 32; off <<= 1) {
            sm[ct] += __shfl_xor(sm[ct], off);
            sq[ct] += __shfl_xor(sq[ct], off);
            mx[ct] = fmaxf(mx[ct], __shfl_xor(mx[ct], off));
            mn[ct] = fminf(mn[ct], __shfl_xor(mn[ct], off));
        }
    }
    // my output feature = lane -> ct = lane>>4 (col part li matches by construction)
    bool s16 = (lane & 16) != 0, s32 = (lane & 32) != 0;
    float S  = s32 ? (s16 ? sm[3] : sm[2]) : (s16 ? sm[1] : sm[0]);
    float Qq = s32 ? (s16 ? sq[3] : sq[2]) : (s16 ? sq[1] : sq[0]);
    float MX = s32 ? (s16 ? mx[3] : mx[2]) : (s16 ? mx[1] : mx[0]);
    float MN = s32 ? (s16 ? mn[3] : mn[2]) : (s16 ? mn[1] : mn[0]);

    float degc = (float)dg;
    float mean_x = S / degc;
    float sd = sqrtf(fmaxf(Qq / degc - mean_x * mean_x, 0.f) + EPS_F);  // shift-invariant
    agg[obase]       = mean_x + p2n;
    agg[obase + 64]  = MX + p2n;
    agg[obase + 128] = MN + p2n;
    agg[obase + 192] = sd;
}

// ---------------- MFMA post: out = hcat_bf16 @ Wpost_bf16 + b; *snorm ----------------
constexpr int LDA = 72;   // shorts per row (144 B, padded)
__global__ __launch_bounds__(256) void postmm_kernel(
    const float* __restrict__ h, const float* __restrict__ snorm,
    const unsigned short* __restrict__ WT, const float* __restrict__ bpost,
    const float* __restrict__ aggb, const int* __restrict__ deg,
    float* __restrict__ out)
{
    __shared__ short A_lds[64 * LDA];   // 9.2 KB

    int tid = threadIdx.x;
    int lane = tid & 63;
    int w = tid >> 6;
    int g = lane >> 4;
    int n0 = blockIdx.x * 64;

    int r = tid >> 2;
    int cgf = (tid & 3) * 16;
    bool vrow = (n0 + r) < N_NODES;

    float aR, bR;
    {
        int dg = vrow ? deg[n0 + r] : 0;
        float degc = fmaxf((float)dg, 1.f);
        float logd = logf(degc + 1.f);
        aR = logd * (1.f / AVG_D_LOG_F);
        bR = AVG_D_LOG_F / logd;
    }

    f32x4 acc[4];
    #pragma unroll
    for (int j = 0; j < 4; ++j) acc[j] = (f32x4){0.f,0.f,0.f,0.f};

    for (int c = 0; c < 13; ++c) {
        unsigned short u[16];
        if (vrow) {
            const float* srow;
            float scl = 1.f;
            if (c == 0) {
                srow = h + (size_t)(n0 + r) * IN_F + cgf;
            } else {
                int q0 = ((c - 1) & 3) * 64;
                srow = aggb + (size_t)(n0 + r) * AGG_F + q0 + cgf;
                int sec = (c - 1) >> 2;
                scl = (sec == 0) ? 1.f : ((sec == 1) ? aR : bR);
            }
            #pragma unroll
            for (int q = 0; q < 4; ++q) {
                float4 v = *reinterpret_cast<const float4*>(srow + 4 * q);
                u[4 * q + 0] = f2bf(v.x * scl);
                u[4 * q + 1] = f2bf(v.y * scl);
                u[4 * q + 2] = f2bf(v.z * scl);
                u[4 * q + 3] = f2bf(v.w * scl);
            }
        } else {
            #pragma unroll
            for (int q = 0; q < 16; ++q) u[q] = 0;
        }
        __syncthreads();
        *reinterpret_cast<short8*>(&A_lds[r * LDA + cgf])     = *reinterpret_cast<short8*>(&u[0]);
        *reinterpret_cast<short8*>(&A_lds[r * LDA + cgf + 8]) = *reinterpret_cast<short8*>(&u[8]);
        __syncthreads();

        int arow = w * 16 + (lane & 15);
        #pragma unroll
        for (int s = 0; s < 2; ++s) {
            short8 af = *reinterpret_cast<const short8*>(&A_lds[arow * LDA + s * 32 + g * 8]);
            int kk = c * 64 + s * 32 + g * 8;
            #pragma unroll
            for (int j = 0; j < 4; ++j) {
                short8 bf = *reinterpret_cast<const short8*>(&WT[(size_t)(j * 16 + (lane & 15)) * KTOT + kk]);
                acc[j] = __builtin_amdgcn_mfma_f32_16x16x32_bf16(af, bf, acc[j], 0, 0, 0);
            }
        }
    }

    float bp[4];
    #pragma unroll
    for (int j = 0; j < 4; ++j) bp[j] = bpost[j * 16 + (lane & 15)];

    #pragma unroll
    for (int rr = 0; rr < 4; ++rr) {
        int node = n0 + w * 16 + g * 4 + rr;
        if (node < N_NODES) {
            float sn = snorm[node];
            #pragma unroll
            for (int j = 0; j < 4; ++j) {
                out[(size_t)node * OUT_F + j * 16 + (lane & 15)] = (acc[j][rr] + bp[j]) * sn;
            }
        }
    }
}

extern "C" void kernel_launch(void* const* d_in, const int* in_sizes, int n_in,
                              void* d_out, int out_size, void* d_ws, size_t ws_size,
                              hipStream_t stream) {
    const float* h     = (const float*)d_in[0];
    const float* ef    = (const float*)d_in[1];
    const float* snorm = (const float*)d_in[2];
    const float* Wpre  = (const float*)d_in[3];
    const float* bpre  = (const float*)d_in[4];
    const float* Wpost = (const float*)d_in[5];
    const float* bpost = (const float*)d_in[6];
    const int* src     = (const int*)d_in[7];
    const int* dst     = (const int*)d_in[8];
    float* out = (float*)d_out;

    char* ws = (char*)d_ws;
    size_t off = 0;
    auto alloc = [&](size_t bytes) { char* p = ws + off; off += (bytes + 255) & ~size_t(255); return p; };
    unsigned short* P1b = (unsigned short*)alloc((size_t)N_NODES * IN_F * 2);   // 6.4 MB
    float* P2      = (float*)alloc((size_t)N_NODES * IN_F * 4);                 // 12.8 MB
    float* agg     = (float*)alloc((size_t)N_NODES * AGG_F * 4);                // 51.2 MB
    int* deg       = (int*)alloc((size_t)N_NODES * 4);
    int* row_start = (int*)alloc((size_t)N_NODES * 4);
    int* cursor    = (int*)alloc((size_t)N_NODES * 4);
    int* csr       = (int*)alloc((size_t)N_EDGES * 4);
    int* bsum      = (int*)alloc((size_t)NBLK_SCAN * 4);
    int* bpre2     = (int*)alloc((size_t)NBLK_SCAN * 4);
    unsigned short* WT   = (unsigned short*)alloc((size_t)OUT_F * KTOT * 2);    // 106 KB
    unsigned short* WefT = (unsigned short*)alloc((size_t)64 * 16 * 2);         // 2 KB

    hipMemsetAsync(deg, 0, (size_t)N_NODES * 4, stream);
    hipLaunchKernelGGL(p12_kernel, dim3((N_NODES + 63) / 64), dim3(256), 0, stream,
                       h, Wpre, bpre, P1b, P2);
    hipLaunchKernelGGL(hist_kernel, dim3((N_EDGES + 255) / 256), dim3(256), 0, stream, dst, deg);
    hipLaunchKernelGGL(scan1_kernel, dim3(NBLK_SCAN), dim3(256), 0, stream, deg, bsum);
    hipLaunchKernelGGL(scan2_kernel, dim3(1), dim3(256), 0, stream, bsum, bpre2);
    hipLaunchKernelGGL(scan3_kernel, dim3(NBLK_SCAN), dim3(256), 0, stream, deg, bpre2, row_start, cursor);
    hipLaunchKernelGGL(scatter_kernel, dim3((N_EDGES + 255) / 256), dim3(256), 0, stream,
                       dst, cursor, csr);
    hipLaunchKernelGGL(wprep_kernel, dim3((OUT_F * KTOT + 255) / 256), dim3(256), 0, stream,
                       Wpost, Wpre, WT, WefT);
    hipLaunchKernelGGL(aggmm_kernel, dim3((N_NODES + 3) / 4), dim3(256), 0, stream,
                       P1b, P2, ef, WefT, src, csr, row_start, deg, agg);
    hipLaunchKernelGGL(postmm_kernel, dim3((N_NODES + 63) / 64), dim3(256), 0, stream,
                       h, snorm, WT, bpost, agg, deg, out);
}

// Round 10
// 229.678 us; speedup vs baseline: 6.6941x; 1.1346x over previous
//
#include <hip/hip_runtime.h>

constexpr int N_NODES = 50000;
constexpr int N_EDGES = 800000;
constexpr int IN_F = 64;
constexpr int ED_F = 16;
constexpr int OUT_F = 64;
constexpr int AGG_F = 256;    // 4*IN
constexpr int KTOT = 832;     // 13*64
constexpr float AVG_D_LOG_F = 2.833f;
constexpr float EPS_F = 1e-5f;

typedef __attribute__((ext_vector_type(8))) short short8;
typedef __attribute__((ext_vector_type(4))) float f32x4;

__device__ __forceinline__ float rl(float v, int l) {
    return __int_as_float(__builtin_amdgcn_readlane(__float_as_int(v), l));
}
__device__ __forceinline__ int rfl(int v) { return __builtin_amdgcn_readfirstlane(v); }
__device__ __forceinline__ unsigned short f2bf(float f) {   // RNE f32->bf16
    unsigned u = __float_as_uint(f);
    unsigned r = (u + 0x7FFFu + ((u >> 16) & 1u)) >> 16;
    return (unsigned short)r;
}
__device__ __forceinline__ float bf2f(unsigned short s) {
    return __uint_as_float(((unsigned)s) << 16);
}

// ---------------- P1(bf16) = h@Wpre[0:64], P2(f32) = h@Wpre[64:128] + b_pre ----------------
__global__ __launch_bounds__(256) void p12_kernel(
    const float* __restrict__ h, const float* __restrict__ Wpre, const float* __restrict__ bpre,
    unsigned short* __restrict__ P1b, float* __restrict__ P2)
{
    __shared__ float WpL[128 * 64];   // 32 KB
    int tid = threadIdx.x;
    int lane = tid & 63;
    int wv = tid >> 6;
    for (int i = tid; i < 128 * 64; i += 256) WpL[i] = Wpre[i];
    float bj = bpre[lane];
    __syncthreads();

    int nbase = blockIdx.x * 64 + wv * 16;
    float hr[16];
    #pragma unroll
    for (int t = 0; t < 16; ++t) {
        int n = nbase + t; if (n >= N_NODES) n = N_NODES - 1;
        hr[t] = h[(size_t)n * IN_F + lane];
    }
    float p1[16], p2[16];
    #pragma unroll
    for (int t = 0; t < 16; ++t) { p1[t] = 0.f; p2[t] = bj; }

    for (int i = 0; i < 64; ++i) {
        float w1 = WpL[i * 64 + lane];
        float w2 = WpL[(64 + i) * 64 + lane];
        #pragma unroll
        for (int t = 0; t < 16; ++t) {
            float x = rl(hr[t], i);
            p1[t] = fmaf(x, w1, p1[t]);
            p2[t] = fmaf(x, w2, p2[t]);
        }
    }
    #pragma unroll
    for (int t = 0; t < 16; ++t) {
        int n = nbase + t;
        if (n < N_NODES) {
            P1b[(size_t)n * IN_F + lane] = f2bf(p1[t]);
            P2[(size_t)n * IN_F + lane] = p2[t];
        }
    }
}

// ---------------- hist + ef->bf16 + weight prep (fused) ----------------
constexpr int HIST_THREADS = ((N_EDGES + 255) / 256) * 256;   // 800000
__global__ __launch_bounds__(256) void hist_kernel(
    const int* __restrict__ dst, const float* __restrict__ ef,
    const float* __restrict__ Wpost, const float* __restrict__ Wpre,
    int* __restrict__ deg, unsigned short* __restrict__ efb,
    unsigned short* __restrict__ WT, unsigned short* __restrict__ WefT)
{
    int gid = blockIdx.x * 256 + threadIdx.x;
    if (gid < N_EDGES) atomicAdd(&deg[dst[gid]], 1);
    // flat ef conversion, coalesced grid-stride
    for (size_t i = gid; i < (size_t)N_EDGES * ED_F; i += HIST_THREADS)
        efb[i] = f2bf(ef[i]);
    if (gid < OUT_F * KTOT) {
        int n = gid / KTOT, k = gid % KTOT;
        WT[gid] = f2bf(Wpost[(size_t)k * OUT_F + n]);
    }
    if (gid < 64 * 16) {
        int n = gid >> 4, k = gid & 15;
        WefT[gid] = f2bf(Wpre[(128 + k) * 64 + n]);
    }
}

// ---------------- 3-phase coalesced scan ----------------
constexpr int NBLK_SCAN = (N_NODES + 255) / 256;   // 196

__global__ __launch_bounds__(256) void scan1_kernel(const int* __restrict__ deg, int* __restrict__ bsum)
{
    __shared__ int ws[4];
    int tid = threadIdx.x, lane = tid & 63, wv = tid >> 6;
    int i = blockIdx.x * 256 + tid;
    int v = (i < N_NODES) ? deg[i] : 0;
    #pragma unroll
    for (int off = 32; off > 0; off >>= 1) v += __shfl_down(v, off);
    if (lane == 0) ws[wv] = v;
    __syncthreads();
    if (tid == 0) bsum[blockIdx.x] = ws[0] + ws[1] + ws[2] + ws[3];
}

__global__ __launch_bounds__(256) void scan2_kernel(const int* __restrict__ bsum, int* __restrict__ bpre)
{
    __shared__ int ws[4];
    int tid = threadIdx.x, lane = tid & 63, wv = tid >> 6;
    int v = (tid < NBLK_SCAN) ? bsum[tid] : 0;
    int sc = v;
    #pragma unroll
    for (int off = 1; off < 64; off <<= 1) {
        int u = __shfl_up(sc, off);
        if (lane >= off) sc += u;
    }
    if (lane == 63) ws[wv] = sc;
    __syncthreads();
    int wbase = 0;
    #pragma unroll
    for (int w = 0; w < 4; ++w) if (w < wv) wbase += ws[w];
    if (tid < NBLK_SCAN) bpre[tid] = wbase + sc - v;   // exclusive
}

__global__ __launch_bounds__(256) void scan3_kernel(
    const int* __restrict__ deg, const int* __restrict__ bpre,
    int* __restrict__ row_start, int* __restrict__ cursor)
{
    __shared__ int ws[4];
    int tid = threadIdx.x, lane = tid & 63, wv = tid >> 6;
    int i = blockIdx.x * 256 + tid;
    int v = (i < N_NODES) ? deg[i] : 0;
    int sc = v;
    #pragma unroll
    for (int off = 1; off < 64; off <<= 1) {
        int u = __shfl_up(sc, off);
        if (lane >= off) sc += u;
    }
    if (lane == 63) ws[wv] = sc;
    __syncthreads();
    int wbase = 0;
    #pragma unroll
    for (int w = 0; w < 4; ++w) if (w < wv) wbase += ws[w];
    int ex = bpre[blockIdx.x] + wbase + sc - v;
    if (i < N_NODES) { row_start[i] = ex; cursor[i] = ex; }
}

// ---------------- scatter (edge id, src id) pairs into CSR slots ----------------
__global__ __launch_bounds__(256) void scatter_kernel(
    const int* __restrict__ dst, const int* __restrict__ src,
    int* __restrict__ cursor, int2* __restrict__ csr2)
{
    int e = blockIdx.x * 256 + threadIdx.x;
    if (e < N_EDGES) {
        int pos = atomicAdd(&cursor[dst[e]], 1);
        csr2[pos] = make_int2(e, src[e]);
    }
}

// ---------------- aggregation via MFMA: one wave per node ----------------
__global__ __launch_bounds__(256) void aggmm_kernel(
    const unsigned short* __restrict__ P1b, const float* __restrict__ P2,
    const unsigned short* __restrict__ efb, const unsigned short* __restrict__ WefT,
    const int2* __restrict__ csr2, const int* __restrict__ row_start,
    const int* __restrict__ deg, unsigned short* __restrict__ aggb)
{
    int tid = threadIdx.x;
    int lane = tid & 63;
    int lg = lane >> 4;        // lane group 0..3
    int li = lane & 15;

    // identity B fragments: only 2 distinct (k_local == li ; k_local == 16+li)
    short8 bI0 = {}, bI1 = {};
    #pragma unroll
    for (int j = 0; j < 8; ++j) {
        int k_local = (lg << 3) + j;
        if (k_local == li)      bI0[j] = (short)0x3F80;
        if (k_local == 16 + li) bI1[j] = (short)0x3F80;
    }
    // Wef fragments: col = ct*16+li, k = lg*8+j (lanes >=32: k>=16 -> zero)
    short8 bE[4];
    #pragma unroll
    for (int ct = 0; ct < 4; ++ct) {
        short8 b = {};
        if (lane < 32)
            b = *reinterpret_cast<const short8*>(WefT + (size_t)(ct * 16 + li) * 16 + (lg << 3));
        bE[ct] = b;
    }

    int n = rfl(blockIdx.x * 4 + (tid >> 6));
    if (n >= N_NODES) return;
    int rs = rfl(row_start[n]);
    int dg = rfl(deg[n]);
    size_t obase = (size_t)n * AGG_F + lane;

    if (dg == 0) {
        aggb[obase] = 0; aggb[obase + 64] = 0;
        aggb[obase + 128] = 0; aggb[obase + 192] = 0;
        return;
    }

    float p2n = P2[(size_t)n * IN_F + lane];
    const float NINF = -__builtin_inff(), PINF = __builtin_inff();
    float sm[4] = {0.f, 0.f, 0.f, 0.f};
    float sq[4] = {0.f, 0.f, 0.f, 0.f};
    float mx[4] = {NINF, NINF, NINF, NINF};
    float mn[4] = {PINF, PINF, PINF, PINF};

    for (int base = 0; base < dg; base += 64) {
        int cnt = dg - base; if (cnt > 64) cnt = 64;
        int2 es = make_int2(0, 0);
        if (lane < cnt) es = csr2[rs + base + lane];
        int eid = es.x, sid = es.y;
        int nrt = (cnt + 15) >> 4;
        for (int rt = 0; rt < nrt; ++rt) {
            int srcidx = rt * 16 + li;
            if (srcidx >= cnt) srcidx = cnt - 1;     // dup-pad: max/min neutral
            int s_l = __shfl(sid, srcidx);
            int e_l = __shfl(eid, srcidx);
            short8 aP0 = *reinterpret_cast<const short8*>(P1b + (size_t)s_l * IN_F + (lg << 3));
            short8 aP1 = *reinterpret_cast<const short8*>(P1b + (size_t)s_l * IN_F + 32 + (lg << 3));
            short8 aE = {};
            if (lane < 32)
                aE = *reinterpret_cast<const short8*>(efb + (size_t)e_l * ED_F + (lg << 3));

            f32x4 c0 = {0.f,0.f,0.f,0.f}, c1 = {0.f,0.f,0.f,0.f};
            f32x4 c2 = {0.f,0.f,0.f,0.f}, c3 = {0.f,0.f,0.f,0.f};
            c0 = __builtin_amdgcn_mfma_f32_16x16x32_bf16(aP0, bI0, c0, 0, 0, 0);
            c1 = __builtin_amdgcn_mfma_f32_16x16x32_bf16(aP0, bI1, c1, 0, 0, 0);
            c2 = __builtin_amdgcn_mfma_f32_16x16x32_bf16(aP1, bI0, c2, 0, 0, 0);
            c3 = __builtin_amdgcn_mfma_f32_16x16x32_bf16(aP1, bI1, c3, 0, 0, 0);
            c0 = __builtin_amdgcn_mfma_f32_16x16x32_bf16(aE, bE[0], c0, 0, 0, 0);
            c1 = __builtin_amdgcn_mfma_f32_16x16x32_bf16(aE, bE[1], c1, 0, 0, 0);
            c2 = __builtin_amdgcn_mfma_f32_16x16x32_bf16(aE, bE[2], c2, 0, 0, 0);
            c3 = __builtin_amdgcn_mfma_f32_16x16x32_bf16(aE, bE[3], c3, 0, 0, 0);

            int rowb = rt * 16 + (lg << 2);
            #pragma unroll
            for (int rr = 0; rr < 4; ++rr) {
                bool v = (rowb + rr) < cnt;           // mask only sum/ssq
                float x0 = c0[rr], x1 = c1[rr], x2 = c2[rr], x3 = c3[rr];
                float z0 = v ? x0 : 0.f, z1 = v ? x1 : 0.f, z2 = v ? x2 : 0.f, z3 = v ? x3 : 0.f;
                sm[0] += z0; sm[1] += z1; sm[2] += z2; sm[3] += z3;
                sq[0] = fmaf(z0, z0, sq[0]); sq[1] = fmaf(z1, z1, sq[1]);
                sq[2] = fmaf(z2, z2, sq[2]); sq[3] = fmaf(z3, z3, sq[3]);
                mx[0] = fmaxf(mx[0], x0); mx[1] = fmaxf(mx[1], x1);
                mx[2] = fmaxf(mx[2], x2); mx[3] = fmaxf(mx[3], x3);
                mn[0] = fminf(mn[0], x0); mn[1] = fminf(mn[1], x1);
                mn[2] = fminf(mn[2], x2); mn[3] = fminf(mn[3], x3);
            }
        }
    }

    // butterfly over lane groups
    #pragma unroll
    for (int ct = 0; ct < 4; ++ct) {
        #pragma unroll
        for (int off = 16; off <= 32; off <<= 1) {
            sm[ct] += __shfl_xor(sm[ct], off);
            sq[ct] += __shfl_xor(sq[ct], off);
            mx[ct] = fmaxf(mx[ct], __shfl_xor(mx[ct], off));
            mn[ct] = fminf(mn[ct], __shfl_xor(mn[ct], off));
        }
    }
    bool s16 = (lane & 16) != 0, s32 = (lane & 32) != 0;
    float S  = s32 ? (s16 ? sm[3] : sm[2]) : (s16 ? sm[1] : sm[0]);
    float Qq = s32 ? (s16 ? sq[3] : sq[2]) : (s16 ? sq[1] : sq[0]);
    float MX = s32 ? (s16 ? mx[3] : mx[2]) : (s16 ? mx[1] : mx[0]);
    float MN = s32 ? (s16 ? mn[3] : mn[2]) : (s16 ? mn[1] : mn[0]);

    float degc = (float)dg;
    float mean_x = S / degc;
    float sd = sqrtf(fmaxf(Qq / degc - mean_x * mean_x, 0.f) + EPS_F);  // shift-invariant
    aggb[obase]       = f2bf(mean_x + p2n);
    aggb[obase + 64]  = f2bf(MX + p2n);
    aggb[obase + 128] = f2bf(MN + p2n);
    aggb[obase + 192] = f2bf(sd);
}

// ---------------- MFMA post: out = hcat_bf16 @ Wpost_bf16 + b; *snorm ----------------
constexpr int LDA = 72;   // shorts per row (144 B, padded)
__global__ __launch_bounds__(256) void postmm_kernel(
    const float* __restrict__ h, const float* __restrict__ snorm,
    const unsigned short* __restrict__ WT, const float* __restrict__ bpost,
    const unsigned short* __restrict__ aggb, const int* __restrict__ deg,
    float* __restrict__ out)
{
    __shared__ short A_lds[64 * LDA];   // 9.2 KB

    int tid = threadIdx.x;
    int lane = tid & 63;
    int w = tid >> 6;
    int g = lane >> 4;
    int n0 = blockIdx.x * 64;

    int r = tid >> 2;
    int cgf = (tid & 3) * 16;
    bool vrow = (n0 + r) < N_NODES;

    float aR, bR;
    {
        int dg = vrow ? deg[n0 + r] : 0;
        float degc = fmaxf((float)dg, 1.f);
        float logd = logf(degc + 1.f);
        aR = logd * (1.f / AVG_D_LOG_F);
        bR = AVG_D_LOG_F / logd;
    }

    f32x4 acc[4];
    #pragma unroll
    for (int j = 0; j < 4; ++j) acc[j] = (f32x4){0.f,0.f,0.f,0.f};

    for (int c = 0; c < 13; ++c) {
        unsigned short u[16];
        if (vrow) {
            if (c == 0) {
                const float* srow = h + (size_t)(n0 + r) * IN_F + cgf;
                #pragma unroll
                for (int q = 0; q < 4; ++q) {
                    float4 v = *reinterpret_cast<const float4*>(srow + 4 * q);
                    u[4 * q + 0] = f2bf(v.x); u[4 * q + 1] = f2bf(v.y);
                    u[4 * q + 2] = f2bf(v.z); u[4 * q + 3] = f2bf(v.w);
                }
            } else {
                int q0 = ((c - 1) & 3) * 64;
                const unsigned short* srow = aggb + (size_t)(n0 + r) * AGG_F + q0 + cgf;
                int sec = (c - 1) >> 2;
                if (sec == 0) {
                    *reinterpret_cast<short8*>(&u[0]) = *reinterpret_cast<const short8*>(srow);
                    *reinterpret_cast<short8*>(&u[8]) = *reinterpret_cast<const short8*>(srow + 8);
                } else {
                    float scl = (sec == 1) ? aR : bR;
                    short8 v0 = *reinterpret_cast<const short8*>(srow);
                    short8 v1 = *reinterpret_cast<const short8*>(srow + 8);
                    #pragma unroll
                    for (int q = 0; q < 8; ++q) {
                        u[q]     = f2bf(bf2f((unsigned short)v0[q]) * scl);
                        u[8 + q] = f2bf(bf2f((unsigned short)v1[q]) * scl);
                    }
                }
            }
        } else {
            #pragma unroll
            for (int q = 0; q < 16; ++q) u[q] = 0;
        }
        __syncthreads();
        *reinterpret_cast<short8*>(&A_lds[r * LDA + cgf])     = *reinterpret_cast<short8*>(&u[0]);
        *reinterpret_cast<short8*>(&A_lds[r * LDA + cgf + 8]) = *reinterpret_cast<short8*>(&u[8]);
        __syncthreads();

        int arow = w * 16 + (lane & 15);
        #pragma unroll
        for (int s = 0; s < 2; ++s) {
            short8 af = *reinterpret_cast<const short8*>(&A_lds[arow * LDA + s * 32 + g * 8]);
            int kk = c * 64 + s * 32 + g * 8;
            #pragma unroll
            for (int j = 0; j < 4; ++j) {
                short8 bf = *reinterpret_cast<const short8*>(&WT[(size_t)(j * 16 + (lane & 15)) * KTOT + kk]);
                acc[j] = __builtin_amdgcn_mfma_f32_16x16x32_bf16(af, bf, acc[j], 0, 0, 0);
            }
        }
    }

    float bp[4];
    #pragma unroll
    for (int j = 0; j < 4; ++j) bp[j] = bpost[j * 16 + (lane & 15)];

    #pragma unroll
    for (int rr = 0; rr < 4; ++rr) {
        int node = n0 + w * 16 + g * 4 + rr;
        if (node < N_NODES) {
            float sn = snorm[node];
            #pragma unroll
            for (int j = 0; j < 4; ++j) {
                out[(size_t)node * OUT_F + j * 16 + (lane & 15)] = (acc[j][rr] + bp[j]) * sn;
            }
        }
    }
}

extern "C" void kernel_launch(void* const* d_in, const int* in_sizes, int n_in,
                              void* d_out, int out_size, void* d_ws, size_t ws_size,
                              hipStream_t stream) {
    const float* h     = (const float*)d_in[0];
    const float* ef    = (const float*)d_in[1];
    const float* snorm = (const float*)d_in[2];
    const float* Wpre  = (const float*)d_in[3];
    const float* bpre  = (const float*)d_in[4];
    const float* Wpost = (const float*)d_in[5];
    const float* bpost = (const float*)d_in[6];
    const int* src     = (const int*)d_in[7];
    const int* dst     = (const int*)d_in[8];
    float* out = (float*)d_out;

    char* ws = (char*)d_ws;
    size_t off = 0;
    auto alloc = [&](size_t bytes) { char* p = ws + off; off += (bytes + 255) & ~size_t(255); return p; };
    unsigned short* P1b  = (unsigned short*)alloc((size_t)N_NODES * IN_F * 2);    // 6.4 MB
    float* P2            = (float*)alloc((size_t)N_NODES * IN_F * 4);             // 12.8 MB
    unsigned short* aggb = (unsigned short*)alloc((size_t)N_NODES * AGG_F * 2);   // 25.6 MB
    unsigned short* efb  = (unsigned short*)alloc((size_t)N_EDGES * ED_F * 2);    // 25.6 MB
    int* deg       = (int*)alloc((size_t)N_NODES * 4);
    int* row_start = (int*)alloc((size_t)N_NODES * 4);
    int* cursor    = (int*)alloc((size_t)N_NODES * 4);
    int2* csr2     = (int2*)alloc((size_t)N_EDGES * 8);                           // 6.4 MB
    int* bsum      = (int*)alloc((size_t)NBLK_SCAN * 4);
    int* bpre2     = (int*)alloc((size_t)NBLK_SCAN * 4);
    unsigned short* WT   = (unsigned short*)alloc((size_t)OUT_F * KTOT * 2);      // 106 KB
    unsigned short* WefT = (unsigned short*)alloc((size_t)64 * 16 * 2);           // 2 KB

    hipMemsetAsync(deg, 0, (size_t)N_NODES * 4, stream);
    hipLaunchKernelGGL(p12_kernel, dim3((N_NODES + 63) / 64), dim3(256), 0, stream,
                       h, Wpre, bpre, P1b, P2);
    hipLaunchKernelGGL(hist_kernel, dim3((N_EDGES + 255) / 256), dim3(256), 0, stream,
                       dst, ef, Wpost, Wpre, deg, efb, WT, WefT);
    hipLaunchKernelGGL(scan1_kernel, dim3(NBLK_SCAN), dim3(256), 0, stream, deg, bsum);
    hipLaunchKernelGGL(scan2_kernel, dim3(1), dim3(256), 0, stream, bsum, bpre2);
    hipLaunchKernelGGL(scan3_kernel, dim3(NBLK_SCAN), dim3(256), 0, stream, deg, bpre2, row_start, cursor);
    hipLaunchKernelGGL(scatter_kernel, dim3((N_EDGES + 255) / 256), dim3(256), 0, stream,
                       dst, src, cursor, csr2);
    hipLaunchKernelGGL(aggmm_kernel, dim3((N_NODES + 3) / 4), dim3(256), 0, stream,
                       P1b, P2, efb, WefT, csr2, row_start, deg, aggb);
    hipLaunchKernelGGL(postmm_kernel, dim3((N_NODES + 63) / 64), dim3(256), 0, stream,
                       h, snorm, WT, bpost, aggb, deg, out);
}